// Round 1
// baseline (428.262 us; speedup 1.0000x reference)
//
#include <hip/hip_runtime.h>

typedef unsigned short u16;
typedef unsigned int u32;
typedef short short8 __attribute__((ext_vector_type(8)));
typedef float f32x4 __attribute__((ext_vector_type(4)));

#define NTOK 1024
#define TT 16384   // N*B*L tokens
#define DD 128
#define NH 8
#define DHH 16
#define KNB 16
#define EPSV 1e-5f

__device__ __forceinline__ u16 f2bf(float f) {
    u32 u = __float_as_uint(f);
    u += 0x7fffu + ((u >> 16) & 1u);
    return (u16)(u >> 16);
}
__device__ __forceinline__ float bf2f(u32 u) { return __uint_as_float(u << 16); }
__device__ __forceinline__ u32 pack2(u16 a, u16 b) { return (u32)a | ((u32)b << 16); }
__device__ __forceinline__ void unpack8(uint4 v, float* f) {
    f[0] = bf2f(v.x & 0xffffu); f[1] = bf2f(v.x >> 16);
    f[2] = bf2f(v.y & 0xffffu); f[3] = bf2f(v.y >> 16);
    f[4] = bf2f(v.z & 0xffffu); f[5] = bf2f(v.z >> 16);
    f[6] = bf2f(v.w & 0xffffu); f[7] = bf2f(v.w >> 16);
}

// ---------------- fp32 -> bf16 convert (x -> Xb) ----------------
__global__ __launch_bounds__(256) void k_cvt(const float* __restrict__ x, u16* __restrict__ xb) {
    int i = blockIdx.x * 256 + threadIdx.x;            // 262144 threads, 8 elems each
    const float4* p = (const float4*)x + (size_t)i * 2;
    float4 a = p[0], b = p[1];
    uint4 o;
    o.x = pack2(f2bf(a.x), f2bf(a.y));
    o.y = pack2(f2bf(a.z), f2bf(a.w));
    o.z = pack2(f2bf(b.x), f2bf(b.y));
    o.w = pack2(f2bf(b.z), f2bf(b.w));
    *((uint4*)xb + i) = o;
}

// ---------------- router logits ----------------
__global__ __launch_bounds__(256) void k_logits(const float* __restrict__ mm, const float* __restrict__ Wr,
                                                const float* __restrict__ br, float* __restrict__ logits) {
    int i = blockIdx.x * 256 + threadIdx.x;            // 4096 = 1024 n * 4 e
    int n = i >> 2, e = i & 3;
    const float4* a = (const float4*)(mm + (size_t)n * DD);
    const float4* w = (const float4*)(Wr + (size_t)e * DD);
    float s = 0.f;
#pragma unroll
    for (int j = 0; j < 32; j++) {
        float4 av = a[j], wv = w[j];
        s += av.x * wv.x + av.y * wv.y + av.z * wv.z + av.w * wv.w;
    }
    logits[i] = s + br[e];
}

// ---------------- routing: softmax, top2, capacity, masks, balance loss ----------------
__global__ __launch_bounds__(1024) void k_route(const float* __restrict__ logits, const int* __restrict__ modix,
                                                float* __restrict__ mask8, float* __restrict__ comb8,
                                                float* __restrict__ cnt8, float* __restrict__ loss) {
    __shared__ u32 routed_sh[NTOK];
    __shared__ unsigned char keep_b[4][NTOK];
    __shared__ float red[16];
    int n = threadIdx.x;
    if (n < 16) red[n] = 0.f;
    float g[4];
    float mx = -1e30f;
#pragma unroll
    for (int e = 0; e < 4; e++) { g[e] = logits[n * 4 + e]; mx = fmaxf(mx, g[e]); }
    float s = 0.f;
#pragma unroll
    for (int e = 0; e < 4; e++) { g[e] = expf(g[e] - mx); s += g[e]; }
    float inv = 1.f / s;
#pragma unroll
    for (int e = 0; e < 4; e++) g[e] *= inv;
    // top2 of gate (ties -> lower index, matching lax.top_k)
    int i0 = 0; float b0 = g[0];
#pragma unroll
    for (int e = 1; e < 4; e++) if (g[e] > b0) { b0 = g[e]; i0 = e; }
    int i1 = -1; float b1v = -1e30f;
#pragma unroll
    for (int e = 0; e < 4; e++) if (e != i0 && g[e] > b1v) { b1v = g[e]; i1 = e; }
    u32 rbits = (1u << i0) | (1u << i1);
    routed_sh[n] = rbits;
    __syncthreads();
    if (n < 4) {  // inclusive cumsum capacity: keep iff cumcount <= N/E = 256
        int c = 0;
        for (int t = 0; t < NTOK; t++) { c += (routed_sh[t] >> n) & 1u; keep_b[n][t] = (c <= 256) ? 1 : 0; }
    }
    __syncthreads();
    float rp[4]; float rsum = 0.f;
#pragma unroll
    for (int e = 0; e < 4; e++) {
        rp[e] = (((rbits >> e) & 1u) && keep_b[e][n]) ? g[e] : 0.f;
        rsum += rp[e];
    }
    bool active = rsum > 0.f;
    // top2 of rprobs (must reproduce lax.top_k filler-index tie-break for the BN mask)
    int j0 = 0; float c0 = rp[0];
#pragma unroll
    for (int e = 1; e < 4; e++) if (rp[e] > c0) { c0 = rp[e]; j0 = e; }
    int j1 = -1; float c1 = -1e30f;
#pragma unroll
    for (int e = 0; e < 4; e++) if (e != j0 && rp[e] > c1) { c1 = rp[e]; j1 = e; }
    float vals[16];
#pragma unroll
    for (int e = 0; e < 4; e++) {
        bool sel = active && (e == j0 || e == j1);
        float mf = sel ? 1.f : 0.f;
        mask8[e * NTOK + n] = mf;
        comb8[e * NTOK + n] = rp[e];   // == sel-gated rprobs (filler slot has rp==0)
        vals[e] = mf;
    }
#pragma unroll
    for (int m = 0; m < 4; m++) {
        float mf = (modix[n * 4 + m] == 1) ? 1.f : 0.f;
        mask8[(4 + m) * NTOK + n] = mf;
        comb8[(4 + m) * NTOK + n] = 0.25f * mf;   // mod_out / Mn folded in
        vals[4 + m] = mf;
    }
#pragma unroll
    for (int e = 0; e < 4; e++) vals[8 + e] = ((rbits >> e) & 1u) ? 1.f : 0.f;  // f_i numerator
#pragma unroll
    for (int e = 0; e < 4; e++) vals[12 + e] = g[e];                            // P_i numerator
    int lane = n & 63;
#pragma unroll
    for (int q = 0; q < 16; q++) {
        float v = vals[q];
        for (int off = 32; off; off >>= 1) v += __shfl_down(v, off, 64);
        if (lane == 0) atomicAdd(&red[q], v);
    }
    __syncthreads();
    if (n == 0) {
        for (int c = 0; c < 8; c++) cnt8[c] = fmaxf(16.f * red[c], 1.f);  // mask broadcast over BL=16
        float l = 0.f;
        for (int e = 0; e < 4; e++) l += (red[8 + e] / 1024.f) * (red[12 + e] / 1024.f);
        loss[0] = 4.f * l;
    }
}

// ---------------- GEMM: fused QKV projection (bf16 MFMA, BM=64, BN=128, K=128) ----------------
__global__ __launch_bounds__(256) void k_gemm_qkv(const u16* __restrict__ Xb,
        const float* __restrict__ Wq, const float* __restrict__ Wk, const float* __restrict__ Wv,
        const float* __restrict__ bq, u16* __restrict__ Qb, u16* __restrict__ Kb, u16* __restrict__ Vb) {
    __shared__ u16 As[64 * 128];
    __shared__ u16 Bs[128 * 128];
    int tid = threadIdx.x; int bm = blockIdx.x; int y = blockIdx.y;
    const float* W = (y == 0) ? Wq : ((y == 1) ? Wk : Wv);
    u16* Op = (y == 0) ? Qb : ((y == 1) ? Kb : Vb);
    const uint4* asrc = (const uint4*)(Xb + (size_t)bm * 64 * 128);
#pragma unroll
    for (int it = 0; it < 4; ++it) {
        int ci = it * 256 + tid;
        uint4 v = asrc[ci];
        int byte = ci * 16; int row = byte >> 8;
        *(uint4*)((char*)As + (byte ^ ((row & 7) << 4))) = v;
    }
    const float4* wsrc = (const float4*)W;
#pragma unroll
    for (int it = 0; it < 16; ++it) {
        int qi = it * 256 + tid;
        float4 f = wsrc[qi];
        int eo = qi * 4; int row = eo >> 7; int byte = eo * 2;
        ushort4 hh; hh.x = f2bf(f.x); hh.y = f2bf(f.y); hh.z = f2bf(f.z); hh.w = f2bf(f.w);
        *(ushort4*)((char*)Bs + (byte ^ ((row & 7) << 4))) = hh;
    }
    __syncthreads();
    int lane = tid & 63, wid = tid >> 6, lr = lane & 15, lg = lane >> 4;
    f32x4 acc[8] = {};
#pragma unroll
    for (int ks = 0; ks < 4; ++ks) {
        int kk = ks * 64 + lg * 16;
        int arow = wid * 16 + lr;
        short8 a = *(const short8*)((const char*)As + ((arow * 256 + kk) ^ ((arow & 7) << 4)));
#pragma unroll
        for (int nc = 0; nc < 8; ++nc) {
            int brow = nc * 16 + lr;
            short8 b = *(const short8*)((const char*)Bs + ((brow * 256 + kk) ^ ((brow & 7) << 4)));
            acc[nc] = __builtin_amdgcn_mfma_f32_16x16x32_bf16(a, b, acc[nc], 0, 0, 0);
        }
    }
    int row0 = bm * 64 + wid * 16 + lg * 4;
    bool hasb = (y == 0);
#pragma unroll
    for (int nc = 0; nc < 8; ++nc) {
        int col = nc * 16 + lr;
        float bb = hasb ? bq[col] : 0.f;
#pragma unroll
        for (int r = 0; r < 4; r++)
            Op[(size_t)(row0 + r) * 128 + col] = f2bf(acc[nc][r] + bb);
    }
}

// ---------------- gather attention (Q/K/V projected; tkv + biases applied analytically) -----
// NOTE: Ob aliases Qb (each thread reads only its own Q row, then overwrites it) — no __restrict__.
__global__ __launch_bounds__(256) void k_attn(const u16* Qb, const u16* __restrict__ Kb,
        const u16* __restrict__ Vb, const float* __restrict__ tkv, const int* __restrict__ idx,
        const float* __restrict__ bk, const float* __restrict__ bv,
        u16* Ob, float* __restrict__ bnsum, float* __restrict__ bnsq) {
    int tid = threadIdx.x;
    if (blockIdx.x == 0 && tid < 128) { bnsum[tid] = 0.f; bnsq[tid] = 0.f; }  // zero stats for this call
    int gid = blockIdx.x * 256 + tid;
    int t = gid >> 3, h = gid & 7, n = t >> 4, bl = t & 15;
    float qv[16];
    {
        const uint4* qp = (const uint4*)(Qb + (size_t)t * 128 + h * 16);
        uint4 q0 = qp[0], q1 = qp[1];
        unpack8(q0, qv); unpack8(q1, qv + 8);
    }
    float qb = 0.f;
#pragma unroll
    for (int i = 0; i < 16; i++) qb += qv[i] * bk[h * 16 + i];
    int gsav[16]; float tsav[16];
#pragma unroll
    for (int k = 0; k < 16; k++) { gsav[k] = idx[n * 16 + k]; tsav[k] = tkv[n * 16 + k]; }
    float scv[16]; float smax = -1e30f;
    for (int k = 0; k < 16; k++) {
        const uint4* kp = (const uint4*)(Kb + (size_t)(gsav[k] * 16 + bl) * 128 + h * 16);
        float kv[16]; unpack8(kp[0], kv); unpack8(kp[1], kv + 8);
        float d = 0.f;
#pragma unroll
        for (int i = 0; i < 16; i++) d += qv[i] * kv[i];
        float sv = 0.25f * (tsav[k] * d + qb);   // 1/sqrt(dh)=0.25 ; k = tkv*kx + bk
        scv[k] = sv; smax = fmaxf(smax, sv);
    }
    float sum = 0.f;
#pragma unroll
    for (int k = 0; k < 16; k++) { scv[k] = expf(scv[k] - smax); sum += scv[k]; }
    float inv = 1.f / sum;
    float o[16];
#pragma unroll
    for (int i = 0; i < 16; i++) o[i] = 0.f;
    for (int k = 0; k < 16; k++) {
        const uint4* vp = (const uint4*)(Vb + (size_t)(gsav[k] * 16 + bl) * 128 + h * 16);
        float vv[16]; unpack8(vp[0], vv); unpack8(vp[1], vv + 8);
        float c = scv[k] * inv * tsav[k];
#pragma unroll
        for (int i = 0; i < 16; i++) o[i] += c * vv[i];
    }
#pragma unroll
    for (int i = 0; i < 16; i++) o[i] += bv[h * 16 + i];   // sum(attn)=1
    uint4 s0, s1;
    s0.x = pack2(f2bf(o[0]), f2bf(o[1]));  s0.y = pack2(f2bf(o[2]), f2bf(o[3]));
    s0.z = pack2(f2bf(o[4]), f2bf(o[5]));  s0.w = pack2(f2bf(o[6]), f2bf(o[7]));
    s1.x = pack2(f2bf(o[8]), f2bf(o[9]));  s1.y = pack2(f2bf(o[10]), f2bf(o[11]));
    s1.z = pack2(f2bf(o[12]), f2bf(o[13])); s1.w = pack2(f2bf(o[14]), f2bf(o[15]));
    uint4* op = (uint4*)(Ob + (size_t)t * 128 + h * 16);
    op[0] = s0; op[1] = s1;
}

// ---------------- GEMM: O @ Wo.T + bo, fused masked BN statistics ----------------
__global__ __launch_bounds__(256) void k_gemm_o(const u16* __restrict__ Ab, const float* __restrict__ Wo,
        const float* __restrict__ bo, float* __restrict__ O2, const float* __restrict__ maskp,
        float* __restrict__ bnsum, float* __restrict__ bnsq) {
    __shared__ u16 As[64 * 128];
    __shared__ u16 Bs[128 * 128];
    __shared__ float ssum[128], ssq[128];
    int tid = threadIdx.x; int bm = blockIdx.x;
    if (tid < 128) { ssum[tid] = 0.f; ssq[tid] = 0.f; }
    const uint4* asrc = (const uint4*)(Ab + (size_t)bm * 64 * 128);
#pragma unroll
    for (int it = 0; it < 4; ++it) {
        int ci = it * 256 + tid;
        uint4 v = asrc[ci];
        int byte = ci * 16; int row = byte >> 8;
        *(uint4*)((char*)As + (byte ^ ((row & 7) << 4))) = v;
    }
    const float4* wsrc = (const float4*)Wo;
#pragma unroll
    for (int it = 0; it < 16; ++it) {
        int qi = it * 256 + tid;
        float4 f = wsrc[qi];
        int eo = qi * 4; int row = eo >> 7; int byte = eo * 2;
        ushort4 hh; hh.x = f2bf(f.x); hh.y = f2bf(f.y); hh.z = f2bf(f.z); hh.w = f2bf(f.w);
        *(ushort4*)((char*)Bs + (byte ^ ((row & 7) << 4))) = hh;
    }
    __syncthreads();
    int lane = tid & 63, wid = tid >> 6, lr = lane & 15, lg = lane >> 4;
    f32x4 acc[8] = {};
#pragma unroll
    for (int ks = 0; ks < 4; ++ks) {
        int kk = ks * 64 + lg * 16;
        int arow = wid * 16 + lr;
        short8 a = *(const short8*)((const char*)As + ((arow * 256 + kk) ^ ((arow & 7) << 4)));
#pragma unroll
        for (int nc = 0; nc < 8; ++nc) {
            int brow = nc * 16 + lr;
            short8 b = *(const short8*)((const char*)Bs + ((brow * 256 + kk) ^ ((brow & 7) << 4)));
            acc[nc] = __builtin_amdgcn_mfma_f32_16x16x32_bf16(a, b, acc[nc], 0, 0, 0);
        }
    }
    int nidx = bm * 4 + wid;          // 16-row frag group == one token-n
    float mk = maskp[nidx];
    int row0 = bm * 64 + wid * 16 + lg * 4;
    float ps[8], pq[8];
#pragma unroll
    for (int nc = 0; nc < 8; ++nc) {
        int col = nc * 16 + lr;
        float bb = bo[col];
        float sv = 0.f, qv = 0.f;
#pragma unroll
        for (int r = 0; r < 4; r++) {
            float v = acc[nc][r] + bb;
            O2[(size_t)(row0 + r) * 128 + col] = v;
            sv += v; qv += v * v;
        }
        ps[nc] = sv * mk; pq[nc] = qv * mk;
    }
#pragma unroll
    for (int nc = 0; nc < 8; ++nc) {
        ps[nc] += __shfl_xor(ps[nc], 16, 64); ps[nc] += __shfl_xor(ps[nc], 32, 64);
        pq[nc] += __shfl_xor(pq[nc], 16, 64); pq[nc] += __shfl_xor(pq[nc], 32, 64);
    }
    if (lane < 16) {
#pragma unroll
        for (int nc = 0; nc < 8; ++nc) {
            atomicAdd(&ssum[nc * 16 + lane], ps[nc]);
            atomicAdd(&ssq[nc * 16 + lane], pq[nc]);
        }
    }
    __syncthreads();
    if (tid < 128) { atomicAdd(&bnsum[tid], ssum[tid]); atomicAdd(&bnsq[tid], ssq[tid]); }
}

// ---------------- GEMM: (BN(O2)+x) @ W1.T + b1, weighted accumulate into out ----------------
__global__ __launch_bounds__(256) void k_gemm_w1(const float* __restrict__ O2, const float* __restrict__ x,
        const float* __restrict__ W1, const float* __restrict__ b1,
        const float* __restrict__ gamma, const float* __restrict__ beta,
        const float* __restrict__ cntp, const float* __restrict__ bnsum, const float* __restrict__ bnsq,
        const float* __restrict__ combp, float* __restrict__ out) {
    __shared__ u16 As[64 * 128];
    __shared__ u16 Bs[128 * 128];
    __shared__ float sc[128], sh[128];
    int tid = threadIdx.x; int bm = blockIdx.x;
    if (tid < 128) {
        float cnt = cntp[0];
        float mean = bnsum[tid] / cnt;
        float var = bnsq[tid] / cnt - mean * mean;
        float rs = rsqrtf(var + EPSV);
        float g = gamma[tid];
        sc[tid] = rs * g;
        sh[tid] = beta[tid] - mean * rs * g;
    }
    __syncthreads();
#pragma unroll
    for (int it = 0; it < 8; ++it) {
        int qi = it * 256 + tid;
        int eo = qi * 4; int row = eo >> 7; int cb = eo & 127;
        float4 ov = *(const float4*)(O2 + (size_t)bm * 64 * 128 + eo);
        float4 xv = *(const float4*)(x + (size_t)bm * 64 * 128 + eo);
        ushort4 hh;
        hh.x = f2bf(ov.x * sc[cb] + sh[cb] + xv.x);
        hh.y = f2bf(ov.y * sc[cb + 1] + sh[cb + 1] + xv.y);
        hh.z = f2bf(ov.z * sc[cb + 2] + sh[cb + 2] + xv.z);
        hh.w = f2bf(ov.w * sc[cb + 3] + sh[cb + 3] + xv.w);
        *(ushort4*)((char*)As + ((eo * 2) ^ ((row & 7) << 4))) = hh;
    }
    const float4* wsrc = (const float4*)W1;
#pragma unroll
    for (int it = 0; it < 16; ++it) {
        int qi = it * 256 + tid;
        float4 f = wsrc[qi];
        int eo = qi * 4; int row = eo >> 7; int byte = eo * 2;
        ushort4 hh; hh.x = f2bf(f.x); hh.y = f2bf(f.y); hh.z = f2bf(f.z); hh.w = f2bf(f.w);
        *(ushort4*)((char*)Bs + (byte ^ ((row & 7) << 4))) = hh;
    }
    __syncthreads();
    int lane = tid & 63, wid = tid >> 6, lr = lane & 15, lg = lane >> 4;
    f32x4 acc[8] = {};
#pragma unroll
    for (int ks = 0; ks < 4; ++ks) {
        int kk = ks * 64 + lg * 16;
        int arow = wid * 16 + lr;
        short8 a = *(const short8*)((const char*)As + ((arow * 256 + kk) ^ ((arow & 7) << 4)));
#pragma unroll
        for (int nc = 0; nc < 8; ++nc) {
            int brow = nc * 16 + lr;
            short8 b = *(const short8*)((const char*)Bs + ((brow * 256 + kk) ^ ((brow & 7) << 4)));
            acc[nc] = __builtin_amdgcn_mfma_f32_16x16x32_bf16(a, b, acc[nc], 0, 0, 0);
        }
    }
    float wc = combp[bm * 4 + wid];
    if (wc != 0.f) {
        int row0 = bm * 64 + wid * 16 + lg * 4;
#pragma unroll
        for (int nc = 0; nc < 8; ++nc) {
            int col = nc * 16 + lr;
            float bb = b1[col];
#pragma unroll
            for (int r = 0; r < 4; r++) {
                size_t oi = (size_t)(row0 + r) * 128 + col;
                out[oi] += wc * (acc[nc][r] + bb);
            }
        }
    }
}

extern "C" void kernel_launch(void* const* d_in, const int* in_sizes, int n_in,
                              void* d_out, int out_size, void* d_ws, size_t ws_size,
                              hipStream_t stream) {
    (void)in_sizes; (void)n_in; (void)ws_size;
    const float* x    = (const float*)d_in[0];
    const float* mm   = (const float*)d_in[1];
    const float* tkv  = (const float*)d_in[2];
    const int*   idx  = (const int*)d_in[3];
    const int*   modi = (const int*)d_in[4];
    const float* Wr   = (const float*)d_in[5];
    const float* br   = (const float*)d_in[6];
    const float* eWq = (const float*)d_in[7],  *eWk = (const float*)d_in[8],  *eWv = (const float*)d_in[9];
    const float* eWo = (const float*)d_in[10], *eW1 = (const float*)d_in[11];
    const float* mWq = (const float*)d_in[12], *mWk = (const float*)d_in[13], *mWv = (const float*)d_in[14];
    const float* mWo = (const float*)d_in[15], *mW2 = (const float*)d_in[16];
    const float* ebq = (const float*)d_in[17], *ebk = (const float*)d_in[18], *ebv = (const float*)d_in[19];
    const float* ebo = (const float*)d_in[20], *eBeta = (const float*)d_in[21], *eb1 = (const float*)d_in[22];
    const float* mbq = (const float*)d_in[23], *mbk = (const float*)d_in[24], *mbv = (const float*)d_in[25];
    const float* mbo = (const float*)d_in[26], *mBeta = (const float*)d_in[27], *mb2 = (const float*)d_in[28];
    const float* eGamma = (const float*)d_in[29], *mGamma = (const float*)d_in[30];
    float* out = (float*)d_out;

    char* wsb = (char*)d_ws;
    u16* Xb = (u16*)wsb;                               // 4 MB
    u16* Qb = (u16*)(wsb + (size_t)4  * 1024 * 1024);  // 4 MB (attention O written in-place)
    u16* Kb = (u16*)(wsb + (size_t)8  * 1024 * 1024);  // 4 MB
    u16* Vb = (u16*)(wsb + (size_t)12 * 1024 * 1024);  // 4 MB
    float* O2 = (float*)Kb;                            // 8 MB, overlaps dead Kb+Vb
    float* logits = (float*)(wsb + (size_t)16 * 1024 * 1024);
    float* comb8 = logits + 4096;
    float* mask8 = comb8 + 8192;
    float* cnt8  = mask8 + 8192;
    float* bnsum = cnt8 + 16;
    float* bnsq  = bnsum + 128;

    hipMemsetAsync(d_out, 0, (size_t)out_size * sizeof(float), stream);
    k_cvt<<<1024, 256, 0, stream>>>(x, Xb);
    k_logits<<<16, 256, 0, stream>>>(mm, Wr, br, logits);
    k_route<<<1, 1024, 0, stream>>>(logits, modi, mask8, comb8, cnt8, out + (size_t)TT * DD);

    for (int c = 0; c < 8; c++) {
        const float *Wq, *Wk, *Wv, *Wo, *W1, *bq, *bkp, *bvp, *bop, *b1, *ga, *be;
        if (c < 4) {
            int e = c;
            Wq = eWq + e * 16384; Wk = eWk + e * 16384; Wv = eWv + e * 16384;
            Wo = eWo + e * 16384; W1 = eW1 + e * 16384;
            bq = ebq + e * 128; bkp = ebk + e * 128; bvp = ebv + e * 128;
            bop = ebo + e * 128; b1 = eb1 + e * 128;
            ga = eGamma + e * 128; be = eBeta + e * 128;
        } else {
            int m = c - 4;
            Wq = mWq + m * 16384; Wk = mWk + m * 16384; Wv = mWv + m * 16384;
            Wo = mWo + m * 16384; W1 = mW2 + m * 16384;
            bq = mbq + m * 128; bkp = mbk + m * 128; bvp = mbv + m * 128;
            bop = mbo + m * 128; b1 = mb2 + m * 128;
            ga = mGamma + m * 128; be = mBeta + m * 128;
        }
        k_gemm_qkv<<<dim3(256, 3), 256, 0, stream>>>(Xb, Wq, Wk, Wv, bq, Qb, Kb, Vb);
        k_attn<<<512, 256, 0, stream>>>(Qb, Kb, Vb, tkv, idx, bkp, bvp, Qb, bnsum, bnsq);
        k_gemm_o<<<256, 256, 0, stream>>>(Qb, Wo, bop, O2, mask8 + c * 1024, bnsum, bnsq);
        k_gemm_w1<<<256, 256, 0, stream>>>(O2, x, W1, b1, ga, be, cnt8 + c, bnsum, bnsq,
                                           comb8 + c * 1024, out);
    }
}

// Round 2
// 309.781 us; speedup vs baseline: 1.3825x; 1.3825x over previous
//
#include <hip/hip_runtime.h>

typedef unsigned short u16;
typedef unsigned int u32;
typedef short short8 __attribute__((ext_vector_type(8)));
typedef float f32x4 __attribute__((ext_vector_type(4)));

#define NTOK 1024
#define TT 16384   // N*B*L tokens
#define DD 128
#define EPSV 1e-5f
#define ST 2097152 // TT*DD, elements per expert-slice

__device__ __forceinline__ u16 f2bf(float f) {
    u32 u = __float_as_uint(f);
    u += 0x7fffu + ((u >> 16) & 1u);
    return (u16)(u >> 16);
}
__device__ __forceinline__ float bf2f(u32 u) { return __uint_as_float(u << 16); }
__device__ __forceinline__ u32 pack2(u16 a, u16 b) { return (u32)a | ((u32)b << 16); }
__device__ __forceinline__ void unpack8(uint4 v, float* f) {
    f[0] = bf2f(v.x & 0xffffu); f[1] = bf2f(v.x >> 16);
    f[2] = bf2f(v.y & 0xffffu); f[3] = bf2f(v.y >> 16);
    f[4] = bf2f(v.z & 0xffffu); f[5] = bf2f(v.z >> 16);
    f[6] = bf2f(v.w & 0xffffu); f[7] = bf2f(v.w >> 16);
}

// ---------------- fp32 -> bf16 convert (x -> Xb) ----------------
__global__ __launch_bounds__(256) void k_cvt(const float* __restrict__ x, u16* __restrict__ xb) {
    int i = blockIdx.x * 256 + threadIdx.x;
    const float4* p = (const float4*)x + (size_t)i * 2;
    float4 a = p[0], b = p[1];
    uint4 o;
    o.x = pack2(f2bf(a.x), f2bf(a.y));
    o.y = pack2(f2bf(a.z), f2bf(a.w));
    o.z = pack2(f2bf(b.x), f2bf(b.y));
    o.w = pack2(f2bf(b.z), f2bf(b.w));
    *((uint4*)xb + i) = o;
}

// ---------------- router logits ----------------
__global__ __launch_bounds__(256) void k_logits(const float* __restrict__ mm, const float* __restrict__ Wr,
                                                const float* __restrict__ br, float* __restrict__ logits) {
    int i = blockIdx.x * 256 + threadIdx.x;            // 4096 = 1024 n * 4 e
    int n = i >> 2, e = i & 3;
    const float4* a = (const float4*)(mm + (size_t)n * DD);
    const float4* w = (const float4*)(Wr + (size_t)e * DD);
    float s = 0.f;
#pragma unroll
    for (int j = 0; j < 32; j++) {
        float4 av = a[j], wv = w[j];
        s += av.x * wv.x + av.y * wv.y + av.z * wv.z + av.w * wv.w;
    }
    logits[i] = s + br[e];
}

// ---------------- routing: softmax, top2, capacity (ballot scan), masks, loss, zero stats ---
__global__ __launch_bounds__(1024) void k_route(const float* __restrict__ logits, const int* __restrict__ modix,
                                                float* __restrict__ mask8, float* __restrict__ comb8,
                                                float* __restrict__ cnt8, float* __restrict__ bnsum,
                                                float* __restrict__ bnsq, float* __restrict__ loss) {
    __shared__ int wsum[4][16];
    __shared__ float red[16];
    int n = threadIdx.x;
    if (n < 16) red[n] = 0.f;
    bnsum[n] = 0.f; bnsq[n] = 0.f;                      // zero [8][128] stats
    float g[4];
    float mx = -1e30f;
#pragma unroll
    for (int e = 0; e < 4; e++) { g[e] = logits[n * 4 + e]; mx = fmaxf(mx, g[e]); }
    float s = 0.f;
#pragma unroll
    for (int e = 0; e < 4; e++) { g[e] = expf(g[e] - mx); s += g[e]; }
    float inv = 1.f / s;
#pragma unroll
    for (int e = 0; e < 4; e++) g[e] *= inv;
    // top2 of gate (ties -> lower index, matching lax.top_k)
    int i0 = 0; float b0 = g[0];
#pragma unroll
    for (int e = 1; e < 4; e++) if (g[e] > b0) { b0 = g[e]; i0 = e; }
    int i1 = -1; float b1v = -1e30f;
#pragma unroll
    for (int e = 0; e < 4; e++) if (e != i0 && g[e] > b1v) { b1v = g[e]; i1 = e; }
    u32 rbits = (1u << i0) | (1u << i1);
    // inclusive cumsum per expert via wave ballot + cross-wave scan; keep iff <= N/E = 256
    int wav = n >> 6, lane = n & 63;
    unsigned long long lm = (~0ull) >> (63 - lane);     // bits 0..lane
    int pre[4];
#pragma unroll
    for (int e = 0; e < 4; e++) {
        unsigned long long m = __ballot((rbits >> e) & 1u);
        pre[e] = __popcll(m & lm);
        if (lane == 63) wsum[e][wav] = __popcll(m);
    }
    __syncthreads();
    float rp[4]; float rsum = 0.f;
#pragma unroll
    for (int e = 0; e < 4; e++) {
        int off = 0;
        for (int w = 0; w < 16; w++) if (w < wav) off += wsum[e][w];
        bool keep = (off + pre[e]) <= 256;
        rp[e] = (((rbits >> e) & 1u) && keep) ? g[e] : 0.f;
        rsum += rp[e];
    }
    bool active = rsum > 0.f;
    // top2 of rprobs (reproduce lax.top_k filler-index tie-break for the BN mask)
    int j0 = 0; float c0 = rp[0];
#pragma unroll
    for (int e = 1; e < 4; e++) if (rp[e] > c0) { c0 = rp[e]; j0 = e; }
    int j1 = -1; float c1 = -1e30f;
#pragma unroll
    for (int e = 0; e < 4; e++) if (e != j0 && rp[e] > c1) { c1 = rp[e]; j1 = e; }
    float vals[16];
#pragma unroll
    for (int e = 0; e < 4; e++) {
        bool sel = active && (e == j0 || e == j1);
        float mf = sel ? 1.f : 0.f;
        mask8[e * NTOK + n] = mf;
        comb8[e * NTOK + n] = rp[e];
        vals[e] = mf;
    }
#pragma unroll
    for (int m = 0; m < 4; m++) {
        float mf = (modix[n * 4 + m] == 1) ? 1.f : 0.f;
        mask8[(4 + m) * NTOK + n] = mf;
        comb8[(4 + m) * NTOK + n] = 0.25f * mf;         // mod_out / Mn folded in
        vals[4 + m] = mf;
    }
#pragma unroll
    for (int e = 0; e < 4; e++) vals[8 + e] = ((rbits >> e) & 1u) ? 1.f : 0.f;
#pragma unroll
    for (int e = 0; e < 4; e++) vals[12 + e] = g[e];
#pragma unroll
    for (int q = 0; q < 16; q++) {
        float v = vals[q];
        for (int off = 32; off; off >>= 1) v += __shfl_down(v, off, 64);
        if (lane == 0) atomicAdd(&red[q], v);
    }
    __syncthreads();
    if (n == 0) {
        for (int c = 0; c < 8; c++) cnt8[c] = fmaxf(16.f * red[c], 1.f);
        float l = 0.f;
        for (int e = 0; e < 4; e++) l += (red[8 + e] / 1024.f) * (red[12 + e] / 1024.f);
        loss[0] = 4.f * l;
    }
}

// ---------------- batched QKV projection: grid (256 bm, 8 c) ----------------
__global__ __launch_bounds__(256) void k_gemm_qkv(const u16* __restrict__ Xb,
        const float* __restrict__ eWq, const float* __restrict__ eWk, const float* __restrict__ eWv,
        const float* __restrict__ mWq, const float* __restrict__ mWk, const float* __restrict__ mWv,
        const float* __restrict__ ebq, const float* __restrict__ mbq,
        u16* __restrict__ Qb, u16* __restrict__ Kb, u16* __restrict__ Vb) {
    __shared__ u16 As[64 * 128];
    __shared__ u16 Bs[128 * 128];
    int tid = threadIdx.x; int bm = blockIdx.x; int c = blockIdx.y;
    const float* Ws[3];
    if (c < 4) { Ws[0] = eWq + c * 16384; Ws[1] = eWk + c * 16384; Ws[2] = eWv + c * 16384; }
    else { int m = c - 4; Ws[0] = mWq + m * 16384; Ws[1] = mWk + m * 16384; Ws[2] = mWv + m * 16384; }
    const float* bq = (c < 4) ? (ebq + c * 128) : (mbq + (c - 4) * 128);
    u16* Os[3] = { Qb + (size_t)c * ST, Kb + (size_t)c * ST, Vb + (size_t)c * ST };

    const uint4* asrc = (const uint4*)(Xb + (size_t)bm * 64 * 128);
#pragma unroll
    for (int it = 0; it < 4; ++it) {
        int ci = it * 256 + tid;
        uint4 v = asrc[ci];
        int byte = ci * 16; int row = byte >> 8;
        *(uint4*)((char*)As + (byte ^ ((row & 7) << 4))) = v;
    }
    __syncthreads();
    int lane = tid & 63, wid = tid >> 6, lr = lane & 15, lg = lane >> 4;
    short8 a[4];
#pragma unroll
    for (int ks = 0; ks < 4; ++ks) {
        int kk = ks * 64 + lg * 16;
        int arow = wid * 16 + lr;
        a[ks] = *(const short8*)((const char*)As + ((arow * 256 + kk) ^ ((arow & 7) << 4)));
    }
    for (int y = 0; y < 3; ++y) {
        const float4* wsrc = (const float4*)Ws[y];
#pragma unroll
        for (int it = 0; it < 16; ++it) {
            int qi = it * 256 + tid;
            float4 f = wsrc[qi];
            int eo = qi * 4; int row = eo >> 7; int byte = eo * 2;
            ushort4 hh; hh.x = f2bf(f.x); hh.y = f2bf(f.y); hh.z = f2bf(f.z); hh.w = f2bf(f.w);
            *(ushort4*)((char*)Bs + (byte ^ ((row & 7) << 4))) = hh;
        }
        __syncthreads();
        f32x4 acc[8] = {};
#pragma unroll
        for (int ks = 0; ks < 4; ++ks) {
            int kk = ks * 64 + lg * 16;
#pragma unroll
            for (int nc = 0; nc < 8; ++nc) {
                int brow = nc * 16 + lr;
                short8 b = *(const short8*)((const char*)Bs + ((brow * 256 + kk) ^ ((brow & 7) << 4)));
                acc[nc] = __builtin_amdgcn_mfma_f32_16x16x32_bf16(a[ks], b, acc[nc], 0, 0, 0);
            }
        }
        int row0 = bm * 64 + wid * 16 + lg * 4;
        u16* Op = Os[y];
        bool hasb = (y == 0);
#pragma unroll
        for (int nc = 0; nc < 8; ++nc) {
            int col = nc * 16 + lr;
            float bb = hasb ? bq[col] : 0.f;
#pragma unroll
            for (int r = 0; r < 4; r++)
                Op[(size_t)(row0 + r) * 128 + col] = f2bf(acc[nc][r] + bb);
        }
        __syncthreads();
    }
}

// ---------------- batched gather attention: grid (512, 8) ----------------
// Ob aliases Qb slice (each thread reads only its own Q row, then overwrites it).
__global__ __launch_bounds__(256) void k_attn(const u16* Qb, const u16* __restrict__ Kb,
        const u16* __restrict__ Vb, const float* __restrict__ tkv, const int* __restrict__ idx,
        const float* __restrict__ ebk, const float* __restrict__ ebv,
        const float* __restrict__ mbk, const float* __restrict__ mbv, u16* Ob) {
    int tid = threadIdx.x; int c = blockIdx.y;
    const u16* Qc = Qb + (size_t)c * ST;
    const u16* Kc = Kb + (size_t)c * ST;
    const u16* Vc = Vb + (size_t)c * ST;
    u16* Oc = Ob + (size_t)c * ST;
    const float* bk = (c < 4) ? (ebk + c * 128) : (mbk + (c - 4) * 128);
    const float* bv = (c < 4) ? (ebv + c * 128) : (mbv + (c - 4) * 128);
    int gid = blockIdx.x * 256 + tid;
    int t = gid >> 3, h = gid & 7, n = t >> 4, bl = t & 15;
    float qv[16];
    {
        const uint4* qp = (const uint4*)(Qc + (size_t)t * 128 + h * 16);
        uint4 q0 = qp[0], q1 = qp[1];
        unpack8(q0, qv); unpack8(q1, qv + 8);
    }
    float qb = 0.f;
#pragma unroll
    for (int i = 0; i < 16; i++) qb += qv[i] * bk[h * 16 + i];
    int gsav[16]; float tsav[16];
#pragma unroll
    for (int k = 0; k < 16; k++) { gsav[k] = idx[n * 16 + k]; tsav[k] = tkv[n * 16 + k]; }
    float scv[16]; float smax = -1e30f;
    for (int k = 0; k < 16; k++) {
        const uint4* kp = (const uint4*)(Kc + (size_t)(gsav[k] * 16 + bl) * 128 + h * 16);
        float kv[16]; unpack8(kp[0], kv); unpack8(kp[1], kv + 8);
        float d = 0.f;
#pragma unroll
        for (int i = 0; i < 16; i++) d += qv[i] * kv[i];
        float sv = 0.25f * (tsav[k] * d + qb);   // 1/sqrt(dh)=0.25 ; k = tkv*kx + bk
        scv[k] = sv; smax = fmaxf(smax, sv);
    }
    float sum = 0.f;
#pragma unroll
    for (int k = 0; k < 16; k++) { scv[k] = expf(scv[k] - smax); sum += scv[k]; }
    float inv = 1.f / sum;
    float o[16];
#pragma unroll
    for (int i = 0; i < 16; i++) o[i] = 0.f;
    for (int k = 0; k < 16; k++) {
        const uint4* vp = (const uint4*)(Vc + (size_t)(gsav[k] * 16 + bl) * 128 + h * 16);
        float vv[16]; unpack8(vp[0], vv); unpack8(vp[1], vv + 8);
        float cc = scv[k] * inv * tsav[k];
#pragma unroll
        for (int i = 0; i < 16; i++) o[i] += cc * vv[i];
    }
#pragma unroll
    for (int i = 0; i < 16; i++) o[i] += bv[h * 16 + i];   // sum(attn)=1
    uint4 s0, s1;
    s0.x = pack2(f2bf(o[0]), f2bf(o[1]));  s0.y = pack2(f2bf(o[2]), f2bf(o[3]));
    s0.z = pack2(f2bf(o[4]), f2bf(o[5]));  s0.w = pack2(f2bf(o[6]), f2bf(o[7]));
    s1.x = pack2(f2bf(o[8]), f2bf(o[9]));  s1.y = pack2(f2bf(o[10]), f2bf(o[11]));
    s1.z = pack2(f2bf(o[12]), f2bf(o[13])); s1.w = pack2(f2bf(o[14]), f2bf(o[15]));
    uint4* op = (uint4*)(Oc + (size_t)t * 128 + h * 16);
    op[0] = s0; op[1] = s1;
}

// ---------------- batched O @ Wo.T + bo with masked BN stats: grid (256, 8) ----------------
__global__ __launch_bounds__(256) void k_gemm_o(const u16* __restrict__ Ab,
        const float* __restrict__ eWo, const float* __restrict__ mWo,
        const float* __restrict__ ebo, const float* __restrict__ mbo,
        float* __restrict__ O2, const float* __restrict__ mask8,
        float* __restrict__ bnsum, float* __restrict__ bnsq) {
    __shared__ u16 As[64 * 128];
    __shared__ u16 Bs[128 * 128];
    __shared__ float ssum[128], ssq[128];
    int tid = threadIdx.x; int bm = blockIdx.x; int c = blockIdx.y;
    const float* Wo = (c < 4) ? (eWo + c * 16384) : (mWo + (c - 4) * 16384);
    const float* bo = (c < 4) ? (ebo + c * 128) : (mbo + (c - 4) * 128);
    const float* maskp = mask8 + c * NTOK;
    if (tid < 128) { ssum[tid] = 0.f; ssq[tid] = 0.f; }
    const uint4* asrc = (const uint4*)(Ab + (size_t)c * ST + (size_t)bm * 64 * 128);
#pragma unroll
    for (int it = 0; it < 4; ++it) {
        int ci = it * 256 + tid;
        uint4 v = asrc[ci];
        int byte = ci * 16; int row = byte >> 8;
        *(uint4*)((char*)As + (byte ^ ((row & 7) << 4))) = v;
    }
    const float4* wsrc = (const float4*)Wo;
#pragma unroll
    for (int it = 0; it < 16; ++it) {
        int qi = it * 256 + tid;
        float4 f = wsrc[qi];
        int eo = qi * 4; int row = eo >> 7; int byte = eo * 2;
        ushort4 hh; hh.x = f2bf(f.x); hh.y = f2bf(f.y); hh.z = f2bf(f.z); hh.w = f2bf(f.w);
        *(ushort4*)((char*)Bs + (byte ^ ((row & 7) << 4))) = hh;
    }
    __syncthreads();
    int lane = tid & 63, wid = tid >> 6, lr = lane & 15, lg = lane >> 4;
    f32x4 acc[8] = {};
#pragma unroll
    for (int ks = 0; ks < 4; ++ks) {
        int kk = ks * 64 + lg * 16;
        int arow = wid * 16 + lr;
        short8 a = *(const short8*)((const char*)As + ((arow * 256 + kk) ^ ((arow & 7) << 4)));
#pragma unroll
        for (int nc = 0; nc < 8; ++nc) {
            int brow = nc * 16 + lr;
            short8 b = *(const short8*)((const char*)Bs + ((brow * 256 + kk) ^ ((brow & 7) << 4)));
            acc[nc] = __builtin_amdgcn_mfma_f32_16x16x32_bf16(a, b, acc[nc], 0, 0, 0);
        }
    }
    int nidx = bm * 4 + wid;
    float mk = maskp[nidx];
    int row0 = bm * 64 + wid * 16 + lg * 4;
    float* O2c = O2 + (size_t)c * ST;
    float ps[8], pq[8];
#pragma unroll
    for (int nc = 0; nc < 8; ++nc) {
        int col = nc * 16 + lr;
        float bb = bo[col];
        float sv = 0.f, qv = 0.f;
#pragma unroll
        for (int r = 0; r < 4; r++) {
            float v = acc[nc][r] + bb;
            O2c[(size_t)(row0 + r) * 128 + col] = v;
            sv += v; qv += v * v;
        }
        ps[nc] = sv * mk; pq[nc] = qv * mk;
    }
#pragma unroll
    for (int nc = 0; nc < 8; ++nc) {
        ps[nc] += __shfl_xor(ps[nc], 16, 64); ps[nc] += __shfl_xor(ps[nc], 32, 64);
        pq[nc] += __shfl_xor(pq[nc], 16, 64); pq[nc] += __shfl_xor(pq[nc], 32, 64);
    }
    if (lane < 16) {
#pragma unroll
        for (int nc = 0; nc < 8; ++nc) {
            atomicAdd(&ssum[nc * 16 + lane], ps[nc]);
            atomicAdd(&ssq[nc * 16 + lane], pq[nc]);
        }
    }
    __syncthreads();
    if (tid < 128) { atomicAdd(&bnsum[c * 128 + tid], ssum[tid]); atomicAdd(&bnsq[c * 128 + tid], ssq[tid]); }
}

// ---------------- fused final GEMM over all 8 experts, single out write: grid 256 ----------------
__global__ __launch_bounds__(256) void k_gemm_w1(const float* __restrict__ O2, const float* __restrict__ x,
        const float* __restrict__ eW1, const float* __restrict__ mW2,
        const float* __restrict__ eb1, const float* __restrict__ mb2,
        const float* __restrict__ eGamma, const float* __restrict__ mGamma,
        const float* __restrict__ eBeta, const float* __restrict__ mBeta,
        const float* __restrict__ comb8, const float* __restrict__ cnt8,
        const float* __restrict__ bnsum, const float* __restrict__ bnsq,
        float* __restrict__ out) {
    __shared__ u16 As[64 * 128];
    __shared__ u16 Bs[128 * 128];
    __shared__ float xs[64 * 128];
    __shared__ float scall[8][128], shall[8][128];
    int tid = threadIdx.x; int bm = blockIdx.x;
    // stage residual x slice (fp32) once
#pragma unroll
    for (int it = 0; it < 8; ++it) {
        int eo = (it * 256 + tid) * 4;
        *(float4*)(xs + eo) = *(const float4*)(x + (size_t)bm * 8192 + eo);
    }
    // BN scale/shift for all 8 experts
#pragma unroll
    for (int j = 0; j < 4; ++j) {
        int id = j * 256 + tid;
        int c = id >> 7, d = id & 127;
        float cnt = cnt8[c];
        float mean = bnsum[c * 128 + d] / cnt;
        float var = bnsq[c * 128 + d] / cnt - mean * mean;
        float rs = rsqrtf(var + EPSV);
        const float* ga = (c < 4) ? (eGamma + c * 128) : (mGamma + (c - 4) * 128);
        const float* be = (c < 4) ? (eBeta + c * 128) : (mBeta + (c - 4) * 128);
        float gg = ga[d];
        scall[c][d] = rs * gg;
        shall[c][d] = be[d] - mean * rs * gg;
    }
    __syncthreads();
    int lane = tid & 63, wid = tid >> 6, lr = lane & 15, lg = lane >> 4;
    f32x4 acc[8] = {};
    for (int c = 0; c < 8; ++c) {
        const float* W1 = (c < 4) ? (eW1 + c * 16384) : (mW2 + (c - 4) * 16384);
        const float* O2c = O2 + (size_t)c * ST + (size_t)bm * 8192;
        // stage A = wc * (BN(O2) + x), bf16
#pragma unroll
        for (int it = 0; it < 8; ++it) {
            int qi = it * 256 + tid;
            int eo = qi * 4; int row = eo >> 7; int cb = eo & 127;
            int n = bm * 4 + (row >> 4);
            float wc = comb8[c * NTOK + n];
            float4 ov = *(const float4*)(O2c + eo);
            ushort4 hh;
            hh.x = f2bf((ov.x * scall[c][cb] + shall[c][cb] + xs[eo]) * wc);
            hh.y = f2bf((ov.y * scall[c][cb + 1] + shall[c][cb + 1] + xs[eo + 1]) * wc);
            hh.z = f2bf((ov.z * scall[c][cb + 2] + shall[c][cb + 2] + xs[eo + 2]) * wc);
            hh.w = f2bf((ov.w * scall[c][cb + 3] + shall[c][cb + 3] + xs[eo + 3]) * wc);
            *(ushort4*)((char*)As + ((eo * 2) ^ ((row & 7) << 4))) = hh;
        }
        const float4* wsrc = (const float4*)W1;
#pragma unroll
        for (int it = 0; it < 16; ++it) {
            int qi = it * 256 + tid;
            float4 f = wsrc[qi];
            int eo = qi * 4; int row = eo >> 7; int byte = eo * 2;
            ushort4 hh; hh.x = f2bf(f.x); hh.y = f2bf(f.y); hh.z = f2bf(f.z); hh.w = f2bf(f.w);
            *(ushort4*)((char*)Bs + (byte ^ ((row & 7) << 4))) = hh;
        }
        __syncthreads();
#pragma unroll
        for (int ks = 0; ks < 4; ++ks) {
            int kk = ks * 64 + lg * 16;
            int arow = wid * 16 + lr;
            short8 a = *(const short8*)((const char*)As + ((arow * 256 + kk) ^ ((arow & 7) << 4)));
#pragma unroll
            for (int nc = 0; nc < 8; ++nc) {
                int brow = nc * 16 + lr;
                short8 b = *(const short8*)((const char*)Bs + ((brow * 256 + kk) ^ ((brow & 7) << 4)));
                acc[nc] = __builtin_amdgcn_mfma_f32_16x16x32_bf16(a, b, acc[nc], 0, 0, 0);
            }
        }
        __syncthreads();
    }
    // epilogue: add Sum_c wc*b1_c and write out once
    int nidx = bm * 4 + wid;
    int row0 = bm * 64 + wid * 16 + lg * 4;
    float wc8[8];
#pragma unroll
    for (int c = 0; c < 8; ++c) wc8[c] = comb8[c * NTOK + nidx];
#pragma unroll
    for (int nc = 0; nc < 8; ++nc) {
        int col = nc * 16 + lr;
        float bias = 0.f;
#pragma unroll
        for (int c = 0; c < 8; ++c) {
            const float* b1 = (c < 4) ? (eb1 + c * 128) : (mb2 + (c - 4) * 128);
            bias += wc8[c] * b1[col];
        }
#pragma unroll
        for (int r = 0; r < 4; r++)
            out[(size_t)(row0 + r) * 128 + col] = acc[nc][r] + bias;
    }
}

extern "C" void kernel_launch(void* const* d_in, const int* in_sizes, int n_in,
                              void* d_out, int out_size, void* d_ws, size_t ws_size,
                              hipStream_t stream) {
    (void)in_sizes; (void)n_in; (void)ws_size; (void)out_size;
    const float* x    = (const float*)d_in[0];
    const float* mm   = (const float*)d_in[1];
    const float* tkv  = (const float*)d_in[2];
    const int*   idx  = (const int*)d_in[3];
    const int*   modi = (const int*)d_in[4];
    const float* Wr   = (const float*)d_in[5];
    const float* br   = (const float*)d_in[6];
    const float* eWq = (const float*)d_in[7],  *eWk = (const float*)d_in[8],  *eWv = (const float*)d_in[9];
    const float* eWo = (const float*)d_in[10], *eW1 = (const float*)d_in[11];
    const float* mWq = (const float*)d_in[12], *mWk = (const float*)d_in[13], *mWv = (const float*)d_in[14];
    const float* mWo = (const float*)d_in[15], *mW2 = (const float*)d_in[16];
    const float* ebq = (const float*)d_in[17], *ebk = (const float*)d_in[18], *ebv = (const float*)d_in[19];
    const float* ebo = (const float*)d_in[20], *eBeta = (const float*)d_in[21], *eb1 = (const float*)d_in[22];
    const float* mbq = (const float*)d_in[23], *mbk = (const float*)d_in[24], *mbv = (const float*)d_in[25];
    const float* mbo = (const float*)d_in[26], *mBeta = (const float*)d_in[27], *mb2 = (const float*)d_in[28];
    const float* eGamma = (const float*)d_in[29], *mGamma = (const float*)d_in[30];
    float* out = (float*)d_out;

    char* wsb = (char*)d_ws;
    const size_t MB = 1024 * 1024;
    u16* Xb = (u16*)wsb;                        // 4 MB
    u16* Qb = (u16*)(wsb + 4 * MB);             // 32 MB (8 expert slices; attn O in-place)
    u16* Kb = (u16*)(wsb + 36 * MB);            // 32 MB
    u16* Vb = (u16*)(wsb + 68 * MB);            // 32 MB
    float* O2 = (float*)(wsb + 36 * MB);        // 64 MB, overlaps dead Kb+Vb
    float* logits = (float*)(wsb + 100 * MB);   // 16 KB
    float* comb8 = logits + 4096;               // [8][1024]
    float* mask8 = comb8 + 8192;                // [8][1024]
    float* cnt8  = mask8 + 8192;                // [8]
    float* bnsum = cnt8 + 16;                   // [8][128]
    float* bnsq  = bnsum + 1024;                // [8][128]

    k_cvt<<<1024, 256, 0, stream>>>(x, Xb);
    k_logits<<<16, 256, 0, stream>>>(mm, Wr, br, logits);
    k_route<<<1, 1024, 0, stream>>>(logits, modi, mask8, comb8, cnt8, bnsum, bnsq,
                                    out + (size_t)TT * DD);
    k_gemm_qkv<<<dim3(256, 8), 256, 0, stream>>>(Xb, eWq, eWk, eWv, mWq, mWk, mWv, ebq, mbq,
                                                 Qb, Kb, Vb);
    k_attn<<<dim3(512, 8), 256, 0, stream>>>(Qb, Kb, Vb, tkv, idx, ebk, ebv, mbk, mbv, Qb);
    k_gemm_o<<<dim3(256, 8), 256, 0, stream>>>(Qb, eWo, mWo, ebo, mbo, O2, mask8, bnsum, bnsq);
    k_gemm_w1<<<256, 256, 0, stream>>>(O2, x, eW1, mW2, eb1, mb2, eGamma, mGamma, eBeta, mBeta,
                                       comb8, cnt8, bnsum, bnsq, out);
}

// Round 4
// 130.954 us; speedup vs baseline: 3.2703x; 2.3656x over previous
//
#include <hip/hip_runtime.h>

typedef unsigned short u16;
typedef unsigned int u32;
typedef short short8 __attribute__((ext_vector_type(8)));
typedef float f32x4 __attribute__((ext_vector_type(4)));

#define NTOK 1024
#define TT 16384   // N*B*L tokens
#define DD 128
#define EPSV 1e-5f
#define ST 2097152 // TT*DD, elements per expert-slice

__device__ __forceinline__ u16 f2bf(float f) {
    u32 u = __float_as_uint(f);
    u += 0x7fffu + ((u >> 16) & 1u);
    return (u16)(u >> 16);
}
__device__ __forceinline__ u32 pack2(u16 a, u16 b) { return (u32)a | ((u32)b << 16); }
// cheap bf16-pair unpack: 1 VALU per element
__device__ __forceinline__ void up2(u32 w, float& lo, float& hi) {
    lo = __uint_as_float(w << 16);
    hi = __uint_as_float(w & 0xffff0000u);
}

// ---------------- fp32 -> bf16 convert (x -> Xb) ----------------
__global__ __launch_bounds__(256) void k_cvt(const float* __restrict__ x, u16* __restrict__ xb) {
    int i = blockIdx.x * 256 + threadIdx.x;
    const float4* p = (const float4*)x + (size_t)i * 2;
    float4 a = p[0], b = p[1];
    uint4 o;
    o.x = pack2(f2bf(a.x), f2bf(a.y));
    o.y = pack2(f2bf(a.z), f2bf(a.w));
    o.z = pack2(f2bf(b.x), f2bf(b.y));
    o.w = pack2(f2bf(b.z), f2bf(b.w));
    *((uint4*)xb + i) = o;
}

// ---------------- all 10 weight tensors -> bf16 (once per call) ----------------
// layout: [eWq0-3, eWk4-7, eWv8-11, eWo12-15, eW1 16-19, mWq20-23, mWk24-27, mWv28-31, mWo32-35, mW2 36-39]
__global__ __launch_bounds__(256) void k_cvtw(const float* __restrict__ eWq, const float* __restrict__ eWk,
        const float* __restrict__ eWv, const float* __restrict__ eWo, const float* __restrict__ eW1,
        const float* __restrict__ mWq, const float* __restrict__ mWk, const float* __restrict__ mWv,
        const float* __restrict__ mWo, const float* __restrict__ mW2, u16* __restrict__ Wb) {
    int i = blockIdx.x * 256 + threadIdx.x;   // 81920 threads, 8 elems each
    int tns = i >> 13;                        // 8192 threads per tensor (65536 elems)
    int off = (i & 8191) * 8;
    const float* src;
    switch (tns) {
        case 0: src = eWq; break; case 1: src = eWk; break; case 2: src = eWv; break;
        case 3: src = eWo; break; case 4: src = eW1; break; case 5: src = mWq; break;
        case 6: src = mWk; break; case 7: src = mWv; break; case 8: src = mWo; break;
        default: src = mW2; break;
    }
    const float4* p = (const float4*)(src + off);
    float4 a = p[0], b = p[1];
    uint4 o;
    o.x = pack2(f2bf(a.x), f2bf(a.y));
    o.y = pack2(f2bf(a.z), f2bf(a.w));
    o.z = pack2(f2bf(b.x), f2bf(b.y));
    o.w = pack2(f2bf(b.z), f2bf(b.w));
    *(uint4*)(Wb + tns * 65536 + off) = o;
}

// ---------------- router logits ----------------
__global__ __launch_bounds__(256) void k_logits(const float* __restrict__ mm, const float* __restrict__ Wr,
                                                const float* __restrict__ br, float* __restrict__ logits) {
    int i = blockIdx.x * 256 + threadIdx.x;            // 4096 = 1024 n * 4 e
    int n = i >> 2, e = i & 3;
    const float4* a = (const float4*)(mm + (size_t)n * DD);
    const float4* w = (const float4*)(Wr + (size_t)e * DD);
    float s = 0.f;
#pragma unroll
    for (int j = 0; j < 32; j++) {
        float4 av = a[j], wv = w[j];
        s += av.x * wv.x + av.y * wv.y + av.z * wv.z + av.w * wv.w;
    }
    logits[i] = s + br[e];
}

// ---------------- routing: softmax, top2, capacity (ballot scan), masks, loss, zero stats ---
__global__ __launch_bounds__(1024) void k_route(const float* __restrict__ logits, const int* __restrict__ modix,
                                                float* __restrict__ mask8, float* __restrict__ comb8,
                                                float* __restrict__ cnt8, float* __restrict__ bnsum,
                                                float* __restrict__ bnsq, float* __restrict__ loss) {
    __shared__ int wsum[4][16];
    __shared__ float red[16];
    int n = threadIdx.x;
    if (n < 16) red[n] = 0.f;
    bnsum[n] = 0.f; bnsq[n] = 0.f;                      // zero [8][128] stats
    float g[4];
    float mx = -1e30f;
#pragma unroll
    for (int e = 0; e < 4; e++) { g[e] = logits[n * 4 + e]; mx = fmaxf(mx, g[e]); }
    float s = 0.f;
#pragma unroll
    for (int e = 0; e < 4; e++) { g[e] = expf(g[e] - mx); s += g[e]; }
    float inv = 1.f / s;
#pragma unroll
    for (int e = 0; e < 4; e++) g[e] *= inv;
    // top2 of gate (ties -> lower index, matching lax.top_k)
    int i0 = 0; float b0 = g[0];
#pragma unroll
    for (int e = 1; e < 4; e++) if (g[e] > b0) { b0 = g[e]; i0 = e; }
    int i1 = -1; float b1v = -1e30f;
#pragma unroll
    for (int e = 0; e < 4; e++) if (e != i0 && g[e] > b1v) { b1v = g[e]; i1 = e; }
    u32 rbits = (1u << i0) | (1u << i1);
    // inclusive cumsum per expert via wave ballot + cross-wave scan; keep iff <= N/E = 256
    int wav = n >> 6, lane = n & 63;
    unsigned long long lm = (~0ull) >> (63 - lane);     // bits 0..lane
    int pre[4];
#pragma unroll
    for (int e = 0; e < 4; e++) {
        unsigned long long m = __ballot((rbits >> e) & 1u);
        pre[e] = __popcll(m & lm);
        if (lane == 63) wsum[e][wav] = __popcll(m);
    }
    __syncthreads();
    float rp[4]; float rsum = 0.f;
#pragma unroll
    for (int e = 0; e < 4; e++) {
        int off = 0;
        for (int w = 0; w < 16; w++) if (w < wav) off += wsum[e][w];
        bool keep = (off + pre[e]) <= 256;
        rp[e] = (((rbits >> e) & 1u) && keep) ? g[e] : 0.f;
        rsum += rp[e];
    }
    bool active = rsum > 0.f;
    // top2 of rprobs (reproduce lax.top_k filler-index tie-break for the BN mask)
    int j0 = 0; float c0 = rp[0];
#pragma unroll
    for (int e = 1; e < 4; e++) if (rp[e] > c0) { c0 = rp[e]; j0 = e; }
    int j1 = -1; float c1 = -1e30f;
#pragma unroll
    for (int e = 0; e < 4; e++) if (e != j0 && rp[e] > c1) { c1 = rp[e]; j1 = e; }
    float vals[16];
#pragma unroll
    for (int e = 0; e < 4; e++) {
        bool sel = active && (e == j0 || e == j1);
        float mf = sel ? 1.f : 0.f;
        mask8[e * NTOK + n] = mf;
        comb8[e * NTOK + n] = rp[e];
        vals[e] = mf;
    }
#pragma unroll
    for (int m = 0; m < 4; m++) {
        float mf = (modix[n * 4 + m] == 1) ? 1.f : 0.f;
        mask8[(4 + m) * NTOK + n] = mf;
        comb8[(4 + m) * NTOK + n] = 0.25f * mf;         // mod_out / Mn folded in
        vals[4 + m] = mf;
    }
#pragma unroll
    for (int e = 0; e < 4; e++) vals[8 + e] = ((rbits >> e) & 1u) ? 1.f : 0.f;
#pragma unroll
    for (int e = 0; e < 4; e++) vals[12 + e] = g[e];
#pragma unroll
    for (int q = 0; q < 16; q++) {
        float v = vals[q];
        for (int off = 32; off; off >>= 1) v += __shfl_down(v, off, 64);
        if (lane == 0) atomicAdd(&red[q], v);
    }
    __syncthreads();
    if (n == 0) {
        for (int c = 0; c < 8; c++) cnt8[c] = fmaxf(16.f * red[c], 1.f);
        float l = 0.f;
        for (int e = 0; e < 4; e++) l += (red[8 + e] / 1024.f) * (red[12 + e] / 1024.f);
        loss[0] = 4.f * l;
    }
}

// ---------------- batched QKV projection: grid (256 bm, 8 c), bf16 weights ----------------
__global__ __launch_bounds__(256) void k_gemm_qkv(const u16* __restrict__ Xb, const u16* __restrict__ Wb,
        const float* __restrict__ ebq, const float* __restrict__ mbq,
        u16* __restrict__ Qb, u16* __restrict__ Kb, u16* __restrict__ Vb) {
    __shared__ u16 As[64 * 128];
    __shared__ u16 Bs[128 * 128];
    int tid = threadIdx.x; int bm = blockIdx.x; int c = blockIdx.y;
    int wq = (c < 4) ? c : 20 + (c - 4);
    int wk = (c < 4) ? 4 + c : 24 + (c - 4);
    int wv = (c < 4) ? 8 + c : 28 + (c - 4);
    const u16* Wsl[3] = { Wb + wq * 16384, Wb + wk * 16384, Wb + wv * 16384 };
    const float* bq = (c < 4) ? (ebq + c * 128) : (mbq + (c - 4) * 128);
    u16* Os[3] = { Qb + (size_t)c * ST, Kb + (size_t)c * ST, Vb + (size_t)c * ST };

    const uint4* asrc = (const uint4*)(Xb + (size_t)bm * 8192);
#pragma unroll
    for (int it = 0; it < 4; ++it) {
        int ci = it * 256 + tid;
        uint4 v = asrc[ci];
        int byte = ci * 16; int row = byte >> 8;
        *(uint4*)((char*)As + (byte ^ ((row & 7) << 4))) = v;
    }
    __syncthreads();
    int lane = tid & 63, wid = tid >> 6, lr = lane & 15, lg = lane >> 4;
    short8 a[4];
#pragma unroll
    for (int ks = 0; ks < 4; ++ks) {
        int kk = ks * 64 + lg * 16;
        int arow = wid * 16 + lr;
        a[ks] = *(const short8*)((const char*)As + ((arow * 256 + kk) ^ ((arow & 7) << 4)));
    }
    for (int y = 0; y < 3; ++y) {
        const uint4* wsrc = (const uint4*)Wsl[y];
#pragma unroll
        for (int it = 0; it < 8; ++it) {
            int qi = it * 256 + tid;
            uint4 v = wsrc[qi];
            int eo = qi * 8; int row = eo >> 7; int byte = eo * 2;
            *(uint4*)((char*)Bs + (byte ^ ((row & 7) << 4))) = v;
        }
        __syncthreads();
        f32x4 acc[8] = {};
#pragma unroll
        for (int ks = 0; ks < 4; ++ks) {
            int kk = ks * 64 + lg * 16;
#pragma unroll
            for (int nc = 0; nc < 8; ++nc) {
                int brow = nc * 16 + lr;
                short8 b = *(const short8*)((const char*)Bs + ((brow * 256 + kk) ^ ((brow & 7) << 4)));
                acc[nc] = __builtin_amdgcn_mfma_f32_16x16x32_bf16(a[ks], b, acc[nc], 0, 0, 0);
            }
        }
        int row0 = bm * 64 + wid * 16 + lg * 4;
        u16* Op = Os[y];
        bool hasb = (y == 0);
#pragma unroll
        for (int nc = 0; nc < 8; ++nc) {
            int col = nc * 16 + lr;
            float bb = hasb ? bq[col] : 0.f;
#pragma unroll
            for (int r = 0; r < 4; r++)
                Op[(size_t)(row0 + r) * 128 + col] = f2bf(acc[nc][r] + bb);
        }
        __syncthreads();
    }
}

// ---------------- gather attention: linear grid 4096, c = bid&7 (XCD pin), mask skip ------
// Ob aliases Qb slice (each thread reads only its own Q row, then overwrites it).
__global__ __launch_bounds__(256) void k_attn(const u16* Qb, const u16* __restrict__ Kb,
        const u16* __restrict__ Vb, const float* __restrict__ tkv, const int* __restrict__ idx,
        const float* __restrict__ ebk, const float* __restrict__ ebv,
        const float* __restrict__ mbk, const float* __restrict__ mbv,
        const float* __restrict__ mask8, u16* Ob) {
    int bid = blockIdx.x;
    int c = bid & 7, inner = bid >> 3;     // expert -> XCD pinning (round-robin dispatch)
    int tid = threadIdx.x;
    int gid = inner * 256 + tid;
    int t = gid >> 3, h = gid & 7, n = t >> 4, bl = t & 15;
    if (mask8[c * NTOK + n] == 0.f) return;          // wave-uniform skip
    const u16* Qc = Qb + (size_t)c * ST;
    const u16* Kc = Kb + (size_t)c * ST;
    const u16* Vc = Vb + (size_t)c * ST;
    u16* Oc = Ob + (size_t)c * ST;
    const float* bk = (c < 4) ? (ebk + c * 128) : (mbk + (c - 4) * 128);
    const float* bv = (c < 4) ? (ebv + c * 128) : (mbv + (c - 4) * 128);
    float qv[16];
    {
        const uint4* qp = (const uint4*)(Qc + (size_t)t * 128 + h * 16);
        uint4 a = qp[0], b = qp[1];
        up2(a.x, qv[0], qv[1]);   up2(a.y, qv[2], qv[3]);
        up2(a.z, qv[4], qv[5]);   up2(a.w, qv[6], qv[7]);
        up2(b.x, qv[8], qv[9]);   up2(b.y, qv[10], qv[11]);
        up2(b.z, qv[12], qv[13]); up2(b.w, qv[14], qv[15]);
    }
    float qb = 0.f;
#pragma unroll
    for (int i = 0; i < 16; i++) qb += qv[i] * bk[h * 16 + i];
    int gsav[16]; float tsav[16];
#pragma unroll
    for (int k = 0; k < 16; k++) { gsav[k] = idx[n * 16 + k]; tsav[k] = tkv[n * 16 + k]; }
    float scv[16]; float smax = -1e30f;
    for (int k = 0; k < 16; k++) {
        const uint4* kp = (const uint4*)(Kc + (size_t)(gsav[k] * 16 + bl) * 128 + h * 16);
        uint4 a = kp[0], b = kp[1];
        float d0 = 0.f, d1 = 0.f, lo, hi;
        up2(a.x, lo, hi); d0 = fmaf(lo, qv[0], d0);  d1 = fmaf(hi, qv[1], d1);
        up2(a.y, lo, hi); d0 = fmaf(lo, qv[2], d0);  d1 = fmaf(hi, qv[3], d1);
        up2(a.z, lo, hi); d0 = fmaf(lo, qv[4], d0);  d1 = fmaf(hi, qv[5], d1);
        up2(a.w, lo, hi); d0 = fmaf(lo, qv[6], d0);  d1 = fmaf(hi, qv[7], d1);
        up2(b.x, lo, hi); d0 = fmaf(lo, qv[8], d0);  d1 = fmaf(hi, qv[9], d1);
        up2(b.y, lo, hi); d0 = fmaf(lo, qv[10], d0); d1 = fmaf(hi, qv[11], d1);
        up2(b.z, lo, hi); d0 = fmaf(lo, qv[12], d0); d1 = fmaf(hi, qv[13], d1);
        up2(b.w, lo, hi); d0 = fmaf(lo, qv[14], d0); d1 = fmaf(hi, qv[15], d1);
        float sv = 0.25f * (tsav[k] * (d0 + d1) + qb);   // k = tkv*kx + bk ; 1/sqrt(dh)=0.25
        scv[k] = sv; smax = fmaxf(smax, sv);
    }
    float sum = 0.f;
#pragma unroll
    for (int k = 0; k < 16; k++) { scv[k] = expf(scv[k] - smax); sum += scv[k]; }
    float inv = 1.f / sum;
    float o[16];
#pragma unroll
    for (int i = 0; i < 16; i++) o[i] = 0.f;
    for (int k = 0; k < 16; k++) {
        const uint4* vp = (const uint4*)(Vc + (size_t)(gsav[k] * 16 + bl) * 128 + h * 16);
        uint4 a = vp[0], b = vp[1];
        float cc = scv[k] * inv * tsav[k];
        float lo, hi;
        up2(a.x, lo, hi); o[0] = fmaf(lo, cc, o[0]);   o[1] = fmaf(hi, cc, o[1]);
        up2(a.y, lo, hi); o[2] = fmaf(lo, cc, o[2]);   o[3] = fmaf(hi, cc, o[3]);
        up2(a.z, lo, hi); o[4] = fmaf(lo, cc, o[4]);   o[5] = fmaf(hi, cc, o[5]);
        up2(a.w, lo, hi); o[6] = fmaf(lo, cc, o[6]);   o[7] = fmaf(hi, cc, o[7]);
        up2(b.x, lo, hi); o[8] = fmaf(lo, cc, o[8]);   o[9] = fmaf(hi, cc, o[9]);
        up2(b.y, lo, hi); o[10] = fmaf(lo, cc, o[10]); o[11] = fmaf(hi, cc, o[11]);
        up2(b.z, lo, hi); o[12] = fmaf(lo, cc, o[12]); o[13] = fmaf(hi, cc, o[13]);
        up2(b.w, lo, hi); o[14] = fmaf(lo, cc, o[14]); o[15] = fmaf(hi, cc, o[15]);
    }
#pragma unroll
    for (int i = 0; i < 16; i++) o[i] += bv[h * 16 + i];   // sum(attn)=1
    uint4 s0, s1;
    s0.x = pack2(f2bf(o[0]), f2bf(o[1]));  s0.y = pack2(f2bf(o[2]), f2bf(o[3]));
    s0.z = pack2(f2bf(o[4]), f2bf(o[5]));  s0.w = pack2(f2bf(o[6]), f2bf(o[7]));
    s1.x = pack2(f2bf(o[8]), f2bf(o[9]));  s1.y = pack2(f2bf(o[10]), f2bf(o[11]));
    s1.z = pack2(f2bf(o[12]), f2bf(o[13])); s1.w = pack2(f2bf(o[14]), f2bf(o[15]));
    uint4* op = (uint4*)(Oc + (size_t)t * 128 + h * 16);
    op[0] = s0; op[1] = s1;
}

// ---------------- O @ Wo.T + bo with masked BN stats; block skip; bf16 O2: grid (256,8) ----
__global__ __launch_bounds__(256) void k_gemm_o(const u16* __restrict__ Ab, const u16* __restrict__ Wb,
        const float* __restrict__ ebo, const float* __restrict__ mbo,
        u16* __restrict__ O2, const float* __restrict__ mask8,
        float* __restrict__ bnsum, float* __restrict__ bnsq) {
    __shared__ u16 As[64 * 128];
    __shared__ u16 Bs[128 * 128];
    __shared__ float ssum[128], ssq[128];
    int tid = threadIdx.x; int bm = blockIdx.x; int c = blockIdx.y;
    const float* maskp = mask8 + c * NTOK;
    // whole-block skip: all 4 tokens masked out => O2 never consumed, no stats
    if (maskp[bm * 4] == 0.f && maskp[bm * 4 + 1] == 0.f &&
        maskp[bm * 4 + 2] == 0.f && maskp[bm * 4 + 3] == 0.f) return;
    int wo = (c < 4) ? 12 + c : 32 + (c - 4);
    const u16* Wp = Wb + wo * 16384;
    const float* bo = (c < 4) ? (ebo + c * 128) : (mbo + (c - 4) * 128);
    if (tid < 128) { ssum[tid] = 0.f; ssq[tid] = 0.f; }
    const uint4* asrc = (const uint4*)(Ab + (size_t)c * ST + (size_t)bm * 8192);
#pragma unroll
    for (int it = 0; it < 4; ++it) {
        int ci = it * 256 + tid;
        uint4 v = asrc[ci];
        int byte = ci * 16; int row = byte >> 8;
        *(uint4*)((char*)As + (byte ^ ((row & 7) << 4))) = v;
    }
    const uint4* wsrc = (const uint4*)Wp;
#pragma unroll
    for (int it = 0; it < 8; ++it) {
        int qi = it * 256 + tid;
        uint4 v = wsrc[qi];
        int eo = qi * 8; int row = eo >> 7; int byte = eo * 2;
        *(uint4*)((char*)Bs + (byte ^ ((row & 7) << 4))) = v;
    }
    __syncthreads();
    int lane = tid & 63, wid = tid >> 6, lr = lane & 15, lg = lane >> 4;
    f32x4 acc[8] = {};
#pragma unroll
    for (int ks = 0; ks < 4; ++ks) {
        int kk = ks * 64 + lg * 16;
        int arow = wid * 16 + lr;
        short8 a = *(const short8*)((const char*)As + ((arow * 256 + kk) ^ ((arow & 7) << 4)));
#pragma unroll
        for (int nc = 0; nc < 8; ++nc) {
            int brow = nc * 16 + lr;
            short8 b = *(const short8*)((const char*)Bs + ((brow * 256 + kk) ^ ((brow & 7) << 4)));
            acc[nc] = __builtin_amdgcn_mfma_f32_16x16x32_bf16(a, b, acc[nc], 0, 0, 0);
        }
    }
    int nidx = bm * 4 + wid;
    float mk = maskp[nidx];
    int row0 = bm * 64 + wid * 16 + lg * 4;
    u16* O2c = O2 + (size_t)c * ST;
    float ps[8], pq[8];
#pragma unroll
    for (int nc = 0; nc < 8; ++nc) {
        int col = nc * 16 + lr;
        float bb = bo[col];
        float sv = 0.f, qv = 0.f;
#pragma unroll
        for (int r = 0; r < 4; r++) {
            float v = acc[nc][r] + bb;
            if (mk != 0.f) O2c[(size_t)(row0 + r) * 128 + col] = f2bf(v);
            sv += v; qv += v * v;
        }
        ps[nc] = sv * mk; pq[nc] = qv * mk;
    }
#pragma unroll
    for (int nc = 0; nc < 8; ++nc) {
        ps[nc] += __shfl_xor(ps[nc], 16, 64); ps[nc] += __shfl_xor(ps[nc], 32, 64);
        pq[nc] += __shfl_xor(pq[nc], 16, 64); pq[nc] += __shfl_xor(pq[nc], 32, 64);
    }
    if (lane < 16) {
#pragma unroll
        for (int nc = 0; nc < 8; ++nc) {
            atomicAdd(&ssum[nc * 16 + lane], ps[nc]);
            atomicAdd(&ssq[nc * 16 + lane], pq[nc]);
        }
    }
    __syncthreads();
    if (tid < 128) { atomicAdd(&bnsum[c * 128 + tid], ssum[tid]); atomicAdd(&bnsq[c * 128 + tid], ssq[tid]); }
}

// ---------------- fused final GEMM over 8 experts with skip, single out write: grid 256 ----
__global__ __launch_bounds__(256) void k_gemm_w1(const u16* __restrict__ O2, const u16* __restrict__ Xb,
        const u16* __restrict__ Wb, const float* __restrict__ eb1, const float* __restrict__ mb2,
        const float* __restrict__ eGamma, const float* __restrict__ mGamma,
        const float* __restrict__ eBeta, const float* __restrict__ mBeta,
        const float* __restrict__ comb8, const float* __restrict__ cnt8,
        const float* __restrict__ bnsum, const float* __restrict__ bnsq,
        float* __restrict__ out) {
    __shared__ u16 As[64 * 128];
    __shared__ u16 Bs[128 * 128];
    __shared__ float scall[8][128], shall[8][128];
    int tid = threadIdx.x; int bm = blockIdx.x;
    // BN scale/shift for all 8 experts
#pragma unroll
    for (int j = 0; j < 4; ++j) {
        int id = j * 256 + tid;
        int c = id >> 7, d = id & 127;
        float cnt = cnt8[c];
        float mean = bnsum[c * 128 + d] / cnt;
        float var = bnsq[c * 128 + d] / cnt - mean * mean;
        float rs = rsqrtf(var + EPSV);
        const float* ga = (c < 4) ? (eGamma + c * 128) : (mGamma + (c - 4) * 128);
        const float* be = (c < 4) ? (eBeta + c * 128) : (mBeta + (c - 4) * 128);
        float gg = ga[d];
        scall[c][d] = rs * gg;
        shall[c][d] = be[d] - mean * rs * gg;
    }
    __syncthreads();
    int lane = tid & 63, wid = tid >> 6, lr = lane & 15, lg = lane >> 4;
    f32x4 acc[8] = {};
    const uint4* xsrc = (const uint4*)(Xb + (size_t)bm * 8192);
    for (int c = 0; c < 8; ++c) {
        float wc4[4];
        wc4[0] = comb8[c * NTOK + bm * 4];     wc4[1] = comb8[c * NTOK + bm * 4 + 1];
        wc4[2] = comb8[c * NTOK + bm * 4 + 2]; wc4[3] = comb8[c * NTOK + bm * 4 + 3];
        if (wc4[0] == 0.f && wc4[1] == 0.f && wc4[2] == 0.f && wc4[3] == 0.f) continue;
        int wsl = (c < 4) ? 16 + c : 36 + (c - 4);
        const u16* Wp = Wb + wsl * 16384;
        const uint4* osrc = (const uint4*)(O2 + (size_t)c * ST + (size_t)bm * 8192);
        // stage A = wc * (BN(O2) + x), bf16  (NOTE: uint4 hh — pack2 returns u32)
#pragma unroll
        for (int it = 0; it < 4; ++it) {
            int qi = it * 256 + tid;
            int eo = qi * 8; int row = eo >> 7; int cb = eo & 127;
            float wc = wc4[it];                    // n = bm*4 + it for this row-group
            uint4 ov = osrc[qi]; uint4 xv = xsrc[qi];
            float olo, ohi, xlo, xhi;
            uint4 hh;
            up2(ov.x, olo, ohi); up2(xv.x, xlo, xhi);
            hh.x = pack2(f2bf((olo * scall[c][cb] + shall[c][cb] + xlo) * wc),
                         f2bf((ohi * scall[c][cb + 1] + shall[c][cb + 1] + xhi) * wc));
            up2(ov.y, olo, ohi); up2(xv.y, xlo, xhi);
            hh.y = pack2(f2bf((olo * scall[c][cb + 2] + shall[c][cb + 2] + xlo) * wc),
                         f2bf((ohi * scall[c][cb + 3] + shall[c][cb + 3] + xhi) * wc));
            up2(ov.z, olo, ohi); up2(xv.z, xlo, xhi);
            hh.z = pack2(f2bf((olo * scall[c][cb + 4] + shall[c][cb + 4] + xlo) * wc),
                         f2bf((ohi * scall[c][cb + 5] + shall[c][cb + 5] + xhi) * wc));
            up2(ov.w, olo, ohi); up2(xv.w, xlo, xhi);
            hh.w = pack2(f2bf((olo * scall[c][cb + 6] + shall[c][cb + 6] + xlo) * wc),
                         f2bf((ohi * scall[c][cb + 7] + shall[c][cb + 7] + xhi) * wc));
            *(uint4*)((char*)As + ((eo * 2) ^ ((row & 7) << 4))) = hh;
        }
        const uint4* wsrc = (const uint4*)Wp;
#pragma unroll
        for (int it = 0; it < 8; ++it) {
            int qi = it * 256 + tid;
            uint4 v = wsrc[qi];
            int eo = qi * 8; int row = eo >> 7; int byte = eo * 2;
            *(uint4*)((char*)Bs + (byte ^ ((row & 7) << 4))) = v;
        }
        __syncthreads();
#pragma unroll
        for (int ks = 0; ks < 4; ++ks) {
            int kk = ks * 64 + lg * 16;
            int arow = wid * 16 + lr;
            short8 a = *(const short8*)((const char*)As + ((arow * 256 + kk) ^ ((arow & 7) << 4)));
#pragma unroll
            for (int nc = 0; nc < 8; ++nc) {
                int brow = nc * 16 + lr;
                short8 b = *(const short8*)((const char*)Bs + ((brow * 256 + kk) ^ ((brow & 7) << 4)));
                acc[nc] = __builtin_amdgcn_mfma_f32_16x16x32_bf16(a, b, acc[nc], 0, 0, 0);
            }
        }
        __syncthreads();
    }
    // epilogue: add Sum_c wc*b1_c and write out once
    int nidx = bm * 4 + wid;
    int row0 = bm * 64 + wid * 16 + lg * 4;
    float wc8[8];
#pragma unroll
    for (int c = 0; c < 8; ++c) wc8[c] = comb8[c * NTOK + nidx];
#pragma unroll
    for (int nc = 0; nc < 8; ++nc) {
        int col = nc * 16 + lr;
        float bias = 0.f;
#pragma unroll
        for (int c = 0; c < 8; ++c) {
            const float* b1 = (c < 4) ? (eb1 + c * 128) : (mb2 + (c - 4) * 128);
            bias += wc8[c] * b1[col];
        }
#pragma unroll
        for (int r = 0; r < 4; r++)
            out[(size_t)(row0 + r) * 128 + col] = acc[nc][r] + bias;
    }
}

extern "C" void kernel_launch(void* const* d_in, const int* in_sizes, int n_in,
                              void* d_out, int out_size, void* d_ws, size_t ws_size,
                              hipStream_t stream) {
    (void)in_sizes; (void)n_in; (void)ws_size; (void)out_size;
    const float* x    = (const float*)d_in[0];
    const float* mm   = (const float*)d_in[1];
    const float* tkv  = (const float*)d_in[2];
    const int*   idx  = (const int*)d_in[3];
    const int*   modi = (const int*)d_in[4];
    const float* Wr   = (const float*)d_in[5];
    const float* br   = (const float*)d_in[6];
    const float* eWq = (const float*)d_in[7],  *eWk = (const float*)d_in[8],  *eWv = (const float*)d_in[9];
    const float* eWo = (const float*)d_in[10], *eW1 = (const float*)d_in[11];
    const float* mWq = (const float*)d_in[12], *mWk = (const float*)d_in[13], *mWv = (const float*)d_in[14];
    const float* mWo = (const float*)d_in[15], *mW2 = (const float*)d_in[16];
    const float* ebq = (const float*)d_in[17], *ebk = (const float*)d_in[18], *ebv = (const float*)d_in[19];
    const float* ebo = (const float*)d_in[20], *eBeta = (const float*)d_in[21], *eb1 = (const float*)d_in[22];
    const float* mbq = (const float*)d_in[23], *mbk = (const float*)d_in[24], *mbv = (const float*)d_in[25];
    const float* mbo = (const float*)d_in[26], *mBeta = (const float*)d_in[27], *mb2 = (const float*)d_in[28];
    const float* eGamma = (const float*)d_in[29], *mGamma = (const float*)d_in[30];
    float* out = (float*)d_out;

    char* wsb = (char*)d_ws;
    const size_t MB = 1024 * 1024;
    u16* Xb = (u16*)wsb;                        // 0..4 MB
    u16* Wb = (u16*)(wsb + 4 * MB);             // 4..5.3 MB (40 x 16384 bf16)
    u16* Qb = (u16*)(wsb + 8 * MB);             // 8..40 MB  (attn O in-place)
    u16* Kb = (u16*)(wsb + 40 * MB);            // 40..72 MB
    u16* Vb = (u16*)(wsb + 72 * MB);            // 72..104 MB
    u16* O2 = (u16*)(wsb + 104 * MB);           // 104..136 MB (bf16)
    float* logits = (float*)(wsb + 136 * MB);
    float* comb8 = logits + 4096;               // [8][1024]
    float* mask8 = comb8 + 8192;                // [8][1024]
    float* cnt8  = mask8 + 8192;                // [8]
    float* bnsum = cnt8 + 16;                   // [8][128]
    float* bnsq  = bnsum + 1024;                // [8][128]

    k_cvt<<<1024, 256, 0, stream>>>(x, Xb);
    k_cvtw<<<320, 256, 0, stream>>>(eWq, eWk, eWv, eWo, eW1, mWq, mWk, mWv, mWo, mW2, Wb);
    k_logits<<<16, 256, 0, stream>>>(mm, Wr, br, logits);
    k_route<<<1, 1024, 0, stream>>>(logits, modi, mask8, comb8, cnt8, bnsum, bnsq,
                                    out + (size_t)TT * DD);
    k_gemm_qkv<<<dim3(256, 8), 256, 0, stream>>>(Xb, Wb, ebq, mbq, Qb, Kb, Vb);
    k_attn<<<4096, 256, 0, stream>>>(Qb, Kb, Vb, tkv, idx, ebk, ebv, mbk, mbv, mask8, Qb);
    k_gemm_o<<<dim3(256, 8), 256, 0, stream>>>(Qb, Wb, ebo, mbo, O2, mask8, bnsum, bnsq);
    k_gemm_w1<<<256, 256, 0, stream>>>(O2, Xb, Wb, eb1, mb2, eGamma, mGamma, eBeta, mBeta,
                                       comb8, cnt8, bnsum, bnsq, out);
}

// Round 5
// 119.043 us; speedup vs baseline: 3.5975x; 1.1001x over previous
//
#include <hip/hip_runtime.h>

typedef unsigned short u16;
typedef unsigned int u32;
typedef short short8 __attribute__((ext_vector_type(8)));
typedef float f32x4 __attribute__((ext_vector_type(4)));

#define NTOK 1024
#define TT 16384   // N*B*L tokens
#define DD 128
#define EPSV 1e-5f
#define ST 2097152 // TT*DD, elements per expert-slice

__device__ __forceinline__ u16 f2bf(float f) {
    u32 u = __float_as_uint(f);
    u += 0x7fffu + ((u >> 16) & 1u);
    return (u16)(u >> 16);
}
__device__ __forceinline__ u32 pack2(u16 a, u16 b) { return (u32)a | ((u32)b << 16); }
// cheap bf16-pair unpack: 1 VALU per element
__device__ __forceinline__ void up2(u32 w, float& lo, float& hi) {
    lo = __uint_as_float(w << 16);
    hi = __uint_as_float(w & 0xffff0000u);
}

// ---------------- fused prep: x->bf16 | weights->bf16 | router logits ----------------
// blocks [0,1024): cvt x ; [1024,1344): cvt weights ; [1344,1360): logits
__global__ __launch_bounds__(256) void k_prep(const float* __restrict__ x,
        const float* __restrict__ eWq, const float* __restrict__ eWk,
        const float* __restrict__ eWv, const float* __restrict__ eWo, const float* __restrict__ eW1,
        const float* __restrict__ mWq, const float* __restrict__ mWk, const float* __restrict__ mWv,
        const float* __restrict__ mWo, const float* __restrict__ mW2,
        const float* __restrict__ mm, const float* __restrict__ Wr, const float* __restrict__ br,
        u16* __restrict__ Xb, u16* __restrict__ Wb, float* __restrict__ logits) {
    int bid = blockIdx.x; int tid = threadIdx.x;
    if (bid < 1024) {
        int i = bid * 256 + tid;
        const float4* p = (const float4*)x + (size_t)i * 2;
        float4 a = p[0], b = p[1];
        uint4 o;
        o.x = pack2(f2bf(a.x), f2bf(a.y));
        o.y = pack2(f2bf(a.z), f2bf(a.w));
        o.z = pack2(f2bf(b.x), f2bf(b.y));
        o.w = pack2(f2bf(b.z), f2bf(b.w));
        *((uint4*)Xb + i) = o;
    } else if (bid < 1344) {
        int i = (bid - 1024) * 256 + tid;     // 81920 threads, 8 elems each
        int tns = i >> 13;
        int off = (i & 8191) * 8;
        const float* src;
        switch (tns) {
            case 0: src = eWq; break; case 1: src = eWk; break; case 2: src = eWv; break;
            case 3: src = eWo; break; case 4: src = eW1; break; case 5: src = mWq; break;
            case 6: src = mWk; break; case 7: src = mWv; break; case 8: src = mWo; break;
            default: src = mW2; break;
        }
        const float4* p = (const float4*)(src + off);
        float4 a = p[0], b = p[1];
        uint4 o;
        o.x = pack2(f2bf(a.x), f2bf(a.y));
        o.y = pack2(f2bf(a.z), f2bf(a.w));
        o.z = pack2(f2bf(b.x), f2bf(b.y));
        o.w = pack2(f2bf(b.z), f2bf(b.w));
        *(uint4*)(Wb + tns * 65536 + off) = o;
    } else {
        int i = (bid - 1344) * 256 + tid;     // 4096 = 1024 n * 4 e
        int n = i >> 2, e = i & 3;
        const float4* a = (const float4*)(mm + (size_t)n * DD);
        const float4* w = (const float4*)(Wr + (size_t)e * DD);
        float s = 0.f;
#pragma unroll
        for (int j = 0; j < 32; j++) {
            float4 av = a[j], wv = w[j];
            s += av.x * wv.x + av.y * wv.y + av.z * wv.z + av.w * wv.w;
        }
        logits[i] = s + br[e];
    }
}

// ---------------- routing: softmax, top2, capacity (ballot scan), masks, loss, zero stats ---
__global__ __launch_bounds__(1024) void k_route(const float* __restrict__ logits, const int* __restrict__ modix,
                                                float* __restrict__ mask8, float* __restrict__ comb8,
                                                float* __restrict__ cnt8, float* __restrict__ bnsum,
                                                float* __restrict__ bnsq, float* __restrict__ loss) {
    __shared__ int wsum[4][16];
    __shared__ float red[16];
    int n = threadIdx.x;
    if (n < 16) red[n] = 0.f;
    bnsum[n] = 0.f; bnsq[n] = 0.f;                      // zero [8][128] stats
    float g[4];
    float mx = -1e30f;
#pragma unroll
    for (int e = 0; e < 4; e++) { g[e] = logits[n * 4 + e]; mx = fmaxf(mx, g[e]); }
    float s = 0.f;
#pragma unroll
    for (int e = 0; e < 4; e++) { g[e] = expf(g[e] - mx); s += g[e]; }
    float inv = 1.f / s;
#pragma unroll
    for (int e = 0; e < 4; e++) g[e] *= inv;
    // top2 of gate (ties -> lower index, matching lax.top_k)
    int i0 = 0; float b0 = g[0];
#pragma unroll
    for (int e = 1; e < 4; e++) if (g[e] > b0) { b0 = g[e]; i0 = e; }
    int i1 = -1; float b1v = -1e30f;
#pragma unroll
    for (int e = 0; e < 4; e++) if (e != i0 && g[e] > b1v) { b1v = g[e]; i1 = e; }
    u32 rbits = (1u << i0) | (1u << i1);
    // inclusive cumsum per expert via wave ballot + cross-wave scan; keep iff <= N/E = 256
    int wav = n >> 6, lane = n & 63;
    unsigned long long lm = (~0ull) >> (63 - lane);     // bits 0..lane
    int pre[4];
#pragma unroll
    for (int e = 0; e < 4; e++) {
        unsigned long long m = __ballot((rbits >> e) & 1u);
        pre[e] = __popcll(m & lm);
        if (lane == 63) wsum[e][wav] = __popcll(m);
    }
    __syncthreads();
    float rp[4]; float rsum = 0.f;
#pragma unroll
    for (int e = 0; e < 4; e++) {
        int off = 0;
        for (int w = 0; w < 16; w++) if (w < wav) off += wsum[e][w];
        bool keep = (off + pre[e]) <= 256;
        rp[e] = (((rbits >> e) & 1u) && keep) ? g[e] : 0.f;
        rsum += rp[e];
    }
    bool active = rsum > 0.f;
    // top2 of rprobs (reproduce lax.top_k filler-index tie-break for the BN mask)
    int j0 = 0; float c0 = rp[0];
#pragma unroll
    for (int e = 1; e < 4; e++) if (rp[e] > c0) { c0 = rp[e]; j0 = e; }
    int j1 = -1; float c1 = -1e30f;
#pragma unroll
    for (int e = 0; e < 4; e++) if (e != j0 && rp[e] > c1) { c1 = rp[e]; j1 = e; }
    float vals[16];
#pragma unroll
    for (int e = 0; e < 4; e++) {
        bool sel = active && (e == j0 || e == j1);
        float mf = sel ? 1.f : 0.f;
        mask8[e * NTOK + n] = mf;
        comb8[e * NTOK + n] = rp[e];
        vals[e] = mf;
    }
#pragma unroll
    for (int m = 0; m < 4; m++) {
        float mf = (modix[n * 4 + m] == 1) ? 1.f : 0.f;
        mask8[(4 + m) * NTOK + n] = mf;
        comb8[(4 + m) * NTOK + n] = 0.25f * mf;         // mod_out / Mn folded in
        vals[4 + m] = mf;
    }
#pragma unroll
    for (int e = 0; e < 4; e++) vals[8 + e] = ((rbits >> e) & 1u) ? 1.f : 0.f;
#pragma unroll
    for (int e = 0; e < 4; e++) vals[12 + e] = g[e];
#pragma unroll
    for (int q = 0; q < 16; q++) {
        float v = vals[q];
        for (int off = 32; off; off >>= 1) v += __shfl_down(v, off, 64);
        if (lane == 0) atomicAdd(&red[q], v);
    }
    __syncthreads();
    if (n == 0) {
        for (int c = 0; c < 8; c++) cnt8[c] = fmaxf(16.f * red[c], 1.f);
        float l = 0.f;
        for (int e = 0; e < 4; e++) l += (red[8 + e] / 1024.f) * (red[12 + e] / 1024.f);
        loss[0] = 4.f * l;
    }
}

// ---------------- batched QKV projection: grid (256 bm, 8 c), bf16 weights, Q mask-skip ----
__global__ __launch_bounds__(256) void k_gemm_qkv(const u16* __restrict__ Xb, const u16* __restrict__ Wb,
        const float* __restrict__ ebq, const float* __restrict__ mbq,
        const float* __restrict__ mask8,
        u16* __restrict__ Qb, u16* __restrict__ Kb, u16* __restrict__ Vb) {
    __shared__ u16 As[64 * 128];
    __shared__ u16 Bs[128 * 128];
    int tid = threadIdx.x; int bm = blockIdx.x; int c = blockIdx.y;
    int wq = (c < 4) ? c : 20 + (c - 4);
    int wk = (c < 4) ? 4 + c : 24 + (c - 4);
    int wv = (c < 4) ? 8 + c : 28 + (c - 4);
    const u16* Wsl[3] = { Wb + wq * 16384, Wb + wk * 16384, Wb + wv * 16384 };
    const float* bq = (c < 4) ? (ebq + c * 128) : (mbq + (c - 4) * 128);
    u16* Os[3] = { Qb + (size_t)c * ST, Kb + (size_t)c * ST, Vb + (size_t)c * ST };
    const float* maskp = mask8 + c * NTOK;
    bool qact = (maskp[bm * 4] != 0.f) || (maskp[bm * 4 + 1] != 0.f) ||
                (maskp[bm * 4 + 2] != 0.f) || (maskp[bm * 4 + 3] != 0.f);

    const uint4* asrc = (const uint4*)(Xb + (size_t)bm * 8192);
#pragma unroll
    for (int it = 0; it < 4; ++it) {
        int ci = it * 256 + tid;
        uint4 v = asrc[ci];
        int byte = ci * 16; int row = byte >> 8;
        *(uint4*)((char*)As + (byte ^ ((row & 7) << 4))) = v;
    }
    __syncthreads();
    int lane = tid & 63, wid = tid >> 6, lr = lane & 15, lg = lane >> 4;
    short8 a[4];
#pragma unroll
    for (int ks = 0; ks < 4; ++ks) {
        int kk = ks * 64 + lg * 16;
        int arow = wid * 16 + lr;
        a[ks] = *(const short8*)((const char*)As + ((arow * 256 + kk) ^ ((arow & 7) << 4)));
    }
    for (int y = 0; y < 3; ++y) {
        if (y == 0 && !qact) continue;   // Q only read for masked tokens (block-uniform skip)
        const uint4* wsrc = (const uint4*)Wsl[y];
#pragma unroll
        for (int it = 0; it < 8; ++it) {
            int qi = it * 256 + tid;
            uint4 v = wsrc[qi];
            int eo = qi * 8; int row = eo >> 7; int byte = eo * 2;
            *(uint4*)((char*)Bs + (byte ^ ((row & 7) << 4))) = v;
        }
        __syncthreads();
        f32x4 acc[8] = {};
#pragma unroll
        for (int ks = 0; ks < 4; ++ks) {
            int kk = ks * 64 + lg * 16;
#pragma unroll
            for (int nc = 0; nc < 8; ++nc) {
                int brow = nc * 16 + lr;
                short8 b = *(const short8*)((const char*)Bs + ((brow * 256 + kk) ^ ((brow & 7) << 4)));
                acc[nc] = __builtin_amdgcn_mfma_f32_16x16x32_bf16(a[ks], b, acc[nc], 0, 0, 0);
            }
        }
        int row0 = bm * 64 + wid * 16 + lg * 4;
        u16* Op = Os[y];
        bool hasb = (y == 0);
#pragma unroll
        for (int nc = 0; nc < 8; ++nc) {
            int col = nc * 16 + lr;
            float bb = hasb ? bq[col] : 0.f;
#pragma unroll
            for (int r = 0; r < 4; r++)
                Op[(size_t)(row0 + r) * 128 + col] = f2bf(acc[nc][r] + bb);
        }
        __syncthreads();
    }
}

// ---------------- gather attention: linear grid 4096, c = bid&7 (XCD pin), mask skip ------
// Ob aliases Qb slice (each thread reads only its own Q row, then overwrites it).
__global__ __launch_bounds__(256) void k_attn(const u16* Qb, const u16* __restrict__ Kb,
        const u16* __restrict__ Vb, const float* __restrict__ tkv, const int* __restrict__ idx,
        const float* __restrict__ ebk, const float* __restrict__ ebv,
        const float* __restrict__ mbk, const float* __restrict__ mbv,
        const float* __restrict__ mask8, u16* Ob) {
    int bid = blockIdx.x;
    int c = bid & 7, inner = bid >> 3;     // expert -> XCD pinning (round-robin dispatch)
    int tid = threadIdx.x;
    int gid = inner * 256 + tid;
    int t = gid >> 3, h = gid & 7;
    int n = __builtin_amdgcn_readfirstlane(t >> 4);   // wave-uniform (8 t per wave, 16 t per n)
    int bl = t & 15;
    if (mask8[c * NTOK + n] == 0.f) return;          // wave-uniform skip
    const u16* Qc = Qb + (size_t)c * ST;
    const u16* Kc = Kb + (size_t)c * ST;
    const u16* Vc = Vb + (size_t)c * ST;
    u16* Oc = Ob + (size_t)c * ST;
    const float* bk = (c < 4) ? (ebk + c * 128) : (mbk + (c - 4) * 128);
    const float* bv = (c < 4) ? (ebv + c * 128) : (mbv + (c - 4) * 128);
    float qv[16];
    {
        const uint4* qp = (const uint4*)(Qc + (size_t)t * 128 + h * 16);
        uint4 a = qp[0], b = qp[1];
        up2(a.x, qv[0], qv[1]);   up2(a.y, qv[2], qv[3]);
        up2(a.z, qv[4], qv[5]);   up2(a.w, qv[6], qv[7]);
        up2(b.x, qv[8], qv[9]);   up2(b.y, qv[10], qv[11]);
        up2(b.z, qv[12], qv[13]); up2(b.w, qv[14], qv[15]);
    }
    float qb = 0.f;
#pragma unroll
    for (int i = 0; i < 16; i++) qb += qv[i] * bk[h * 16 + i];
    int gsav[16]; float tsav[16];
#pragma unroll
    for (int k = 0; k < 16; k++) { gsav[k] = idx[n * 16 + k]; tsav[k] = tkv[n * 16 + k]; }
    float scv[16]; float smax = -1e30f;
#pragma unroll 2
    for (int k = 0; k < 16; k++) {
        const uint4* kp = (const uint4*)(Kc + (size_t)(gsav[k] * 16 + bl) * 128 + h * 16);
        uint4 a = kp[0], b = kp[1];
        float d0 = 0.f, d1 = 0.f, lo, hi;
        up2(a.x, lo, hi); d0 = fmaf(lo, qv[0], d0);  d1 = fmaf(hi, qv[1], d1);
        up2(a.y, lo, hi); d0 = fmaf(lo, qv[2], d0);  d1 = fmaf(hi, qv[3], d1);
        up2(a.z, lo, hi); d0 = fmaf(lo, qv[4], d0);  d1 = fmaf(hi, qv[5], d1);
        up2(a.w, lo, hi); d0 = fmaf(lo, qv[6], d0);  d1 = fmaf(hi, qv[7], d1);
        up2(b.x, lo, hi); d0 = fmaf(lo, qv[8], d0);  d1 = fmaf(hi, qv[9], d1);
        up2(b.y, lo, hi); d0 = fmaf(lo, qv[10], d0); d1 = fmaf(hi, qv[11], d1);
        up2(b.z, lo, hi); d0 = fmaf(lo, qv[12], d0); d1 = fmaf(hi, qv[13], d1);
        up2(b.w, lo, hi); d0 = fmaf(lo, qv[14], d0); d1 = fmaf(hi, qv[15], d1);
        float sv = 0.25f * (tsav[k] * (d0 + d1) + qb);   // k = tkv*kx + bk ; 1/sqrt(dh)=0.25
        scv[k] = sv; smax = fmaxf(smax, sv);
    }
    float sum = 0.f;
#pragma unroll
    for (int k = 0; k < 16; k++) { scv[k] = expf(scv[k] - smax); sum += scv[k]; }
    float inv = 1.f / sum;
    float o[16];
#pragma unroll
    for (int i = 0; i < 16; i++) o[i] = 0.f;
#pragma unroll 2
    for (int k = 0; k < 16; k++) {
        const uint4* vp = (const uint4*)(Vc + (size_t)(gsav[k] * 16 + bl) * 128 + h * 16);
        uint4 a = vp[0], b = vp[1];
        float cc = scv[k] * inv * tsav[k];
        float lo, hi;
        up2(a.x, lo, hi); o[0] = fmaf(lo, cc, o[0]);   o[1] = fmaf(hi, cc, o[1]);
        up2(a.y, lo, hi); o[2] = fmaf(lo, cc, o[2]);   o[3] = fmaf(hi, cc, o[3]);
        up2(a.z, lo, hi); o[4] = fmaf(lo, cc, o[4]);   o[5] = fmaf(hi, cc, o[5]);
        up2(a.w, lo, hi); o[6] = fmaf(lo, cc, o[6]);   o[7] = fmaf(hi, cc, o[7]);
        up2(b.x, lo, hi); o[8] = fmaf(lo, cc, o[8]);   o[9] = fmaf(hi, cc, o[9]);
        up2(b.y, lo, hi); o[10] = fmaf(lo, cc, o[10]); o[11] = fmaf(hi, cc, o[11]);
        up2(b.z, lo, hi); o[12] = fmaf(lo, cc, o[12]); o[13] = fmaf(hi, cc, o[13]);
        up2(b.w, lo, hi); o[14] = fmaf(lo, cc, o[14]); o[15] = fmaf(hi, cc, o[15]);
    }
#pragma unroll
    for (int i = 0; i < 16; i++) o[i] += bv[h * 16 + i];   // sum(attn)=1
    uint4 s0, s1;
    s0.x = pack2(f2bf(o[0]), f2bf(o[1]));  s0.y = pack2(f2bf(o[2]), f2bf(o[3]));
    s0.z = pack2(f2bf(o[4]), f2bf(o[5]));  s0.w = pack2(f2bf(o[6]), f2bf(o[7]));
    s1.x = pack2(f2bf(o[8]), f2bf(o[9]));  s1.y = pack2(f2bf(o[10]), f2bf(o[11]));
    s1.z = pack2(f2bf(o[12]), f2bf(o[13])); s1.w = pack2(f2bf(o[14]), f2bf(o[15]));
    uint4* op = (uint4*)(Oc + (size_t)t * 128 + h * 16);
    op[0] = s0; op[1] = s1;
}

// ---------------- O @ Wo.T + bo with masked BN stats; block skip; bf16 O2: grid (256,8) ----
__global__ __launch_bounds__(256) void k_gemm_o(const u16* __restrict__ Ab, const u16* __restrict__ Wb,
        const float* __restrict__ ebo, const float* __restrict__ mbo,
        u16* __restrict__ O2, const float* __restrict__ mask8,
        float* __restrict__ bnsum, float* __restrict__ bnsq) {
    __shared__ u16 As[64 * 128];
    __shared__ u16 Bs[128 * 128];
    __shared__ float ssum[128], ssq[128];
    int tid = threadIdx.x; int bm = blockIdx.x; int c = blockIdx.y;
    const float* maskp = mask8 + c * NTOK;
    // whole-block skip: all 4 tokens masked out => O2 never consumed, no stats
    if (maskp[bm * 4] == 0.f && maskp[bm * 4 + 1] == 0.f &&
        maskp[bm * 4 + 2] == 0.f && maskp[bm * 4 + 3] == 0.f) return;
    int wo = (c < 4) ? 12 + c : 32 + (c - 4);
    const u16* Wp = Wb + wo * 16384;
    const float* bo = (c < 4) ? (ebo + c * 128) : (mbo + (c - 4) * 128);
    if (tid < 128) { ssum[tid] = 0.f; ssq[tid] = 0.f; }
    const uint4* asrc = (const uint4*)(Ab + (size_t)c * ST + (size_t)bm * 8192);
#pragma unroll
    for (int it = 0; it < 4; ++it) {
        int ci = it * 256 + tid;
        uint4 v = asrc[ci];
        int byte = ci * 16; int row = byte >> 8;
        *(uint4*)((char*)As + (byte ^ ((row & 7) << 4))) = v;
    }
    const uint4* wsrc = (const uint4*)Wp;
#pragma unroll
    for (int it = 0; it < 8; ++it) {
        int qi = it * 256 + tid;
        uint4 v = wsrc[qi];
        int eo = qi * 8; int row = eo >> 7; int byte = eo * 2;
        *(uint4*)((char*)Bs + (byte ^ ((row & 7) << 4))) = v;
    }
    __syncthreads();
    int lane = tid & 63, wid = tid >> 6, lr = lane & 15, lg = lane >> 4;
    f32x4 acc[8] = {};
#pragma unroll
    for (int ks = 0; ks < 4; ++ks) {
        int kk = ks * 64 + lg * 16;
        int arow = wid * 16 + lr;
        short8 a = *(const short8*)((const char*)As + ((arow * 256 + kk) ^ ((arow & 7) << 4)));
#pragma unroll
        for (int nc = 0; nc < 8; ++nc) {
            int brow = nc * 16 + lr;
            short8 b = *(const short8*)((const char*)Bs + ((brow * 256 + kk) ^ ((brow & 7) << 4)));
            acc[nc] = __builtin_amdgcn_mfma_f32_16x16x32_bf16(a, b, acc[nc], 0, 0, 0);
        }
    }
    int nidx = bm * 4 + wid;
    float mk = maskp[nidx];
    int row0 = bm * 64 + wid * 16 + lg * 4;
    u16* O2c = O2 + (size_t)c * ST;
    float ps[8], pq[8];
#pragma unroll
    for (int nc = 0; nc < 8; ++nc) {
        int col = nc * 16 + lr;
        float bb = bo[col];
        float sv = 0.f, qv = 0.f;
#pragma unroll
        for (int r = 0; r < 4; r++) {
            float v = acc[nc][r] + bb;
            if (mk != 0.f) O2c[(size_t)(row0 + r) * 128 + col] = f2bf(v);
            sv += v; qv += v * v;
        }
        ps[nc] = sv * mk; pq[nc] = qv * mk;
    }
#pragma unroll
    for (int nc = 0; nc < 8; ++nc) {
        ps[nc] += __shfl_xor(ps[nc], 16, 64); ps[nc] += __shfl_xor(ps[nc], 32, 64);
        pq[nc] += __shfl_xor(pq[nc], 16, 64); pq[nc] += __shfl_xor(pq[nc], 32, 64);
    }
    if (lane < 16) {
#pragma unroll
        for (int nc = 0; nc < 8; ++nc) {
            atomicAdd(&ssum[nc * 16 + lane], ps[nc]);
            atomicAdd(&ssq[nc * 16 + lane], pq[nc]);
        }
    }
    __syncthreads();
    if (tid < 128) { atomicAdd(&bnsum[c * 128 + tid], ssum[tid]); atomicAdd(&bnsq[c * 128 + tid], ssq[tid]); }
}

// ---------------- fused final GEMM over 8 experts, 512 threads (8 waves): grid 256 ----------
__global__ __launch_bounds__(512) void k_gemm_w1(const u16* __restrict__ O2, const u16* __restrict__ Xb,
        const u16* __restrict__ Wb, const float* __restrict__ eb1, const float* __restrict__ mb2,
        const float* __restrict__ eGamma, const float* __restrict__ mGamma,
        const float* __restrict__ eBeta, const float* __restrict__ mBeta,
        const float* __restrict__ comb8, const float* __restrict__ cnt8,
        const float* __restrict__ bnsum, const float* __restrict__ bnsq,
        float* __restrict__ out) {
    __shared__ u16 As[64 * 128];
    __shared__ u16 Bs[128 * 128];
    __shared__ float scall[8][128], shall[8][128];
    int tid = threadIdx.x; int bm = blockIdx.x;
    // BN scale/shift for all 8 experts
#pragma unroll
    for (int j = 0; j < 2; ++j) {
        int id = j * 512 + tid;
        int c = id >> 7, d = id & 127;
        float cnt = cnt8[c];
        float mean = bnsum[c * 128 + d] / cnt;
        float var = bnsq[c * 128 + d] / cnt - mean * mean;
        float rs = rsqrtf(var + EPSV);
        const float* ga = (c < 4) ? (eGamma + c * 128) : (mGamma + (c - 4) * 128);
        const float* be = (c < 4) ? (eBeta + c * 128) : (mBeta + (c - 4) * 128);
        float gg = ga[d];
        scall[c][d] = rs * gg;
        shall[c][d] = be[d] - mean * rs * gg;
    }
    __syncthreads();
    int lane = tid & 63, wid = tid >> 6, lr = lane & 15, lg = lane >> 4;
    int wm = wid & 3, wn = wid >> 2;        // 4 m-frags x 2 n-halves
    f32x4 acc[4] = {};
    const uint4* xsrc = (const uint4*)(Xb + (size_t)bm * 8192);
    for (int c = 0; c < 8; ++c) {
        float wc4[4];
        wc4[0] = comb8[c * NTOK + bm * 4];     wc4[1] = comb8[c * NTOK + bm * 4 + 1];
        wc4[2] = comb8[c * NTOK + bm * 4 + 2]; wc4[3] = comb8[c * NTOK + bm * 4 + 3];
        if (wc4[0] == 0.f && wc4[1] == 0.f && wc4[2] == 0.f && wc4[3] == 0.f) continue;
        int wsl = (c < 4) ? 16 + c : 36 + (c - 4);
        const u16* Wp = Wb + wsl * 16384;
        const uint4* osrc = (const uint4*)(O2 + (size_t)c * ST + (size_t)bm * 8192);
        // stage A = wc * (BN(O2) + x), bf16
#pragma unroll
        for (int it = 0; it < 2; ++it) {
            int qi = it * 512 + tid;
            int eo = qi * 8; int row = eo >> 7; int cb = eo & 127;
            float wc = wc4[row >> 4];
            uint4 ov = osrc[qi]; uint4 xv = xsrc[qi];
            float olo, ohi, xlo, xhi;
            uint4 hh;
            up2(ov.x, olo, ohi); up2(xv.x, xlo, xhi);
            hh.x = pack2(f2bf((olo * scall[c][cb] + shall[c][cb] + xlo) * wc),
                         f2bf((ohi * scall[c][cb + 1] + shall[c][cb + 1] + xhi) * wc));
            up2(ov.y, olo, ohi); up2(xv.y, xlo, xhi);
            hh.y = pack2(f2bf((olo * scall[c][cb + 2] + shall[c][cb + 2] + xlo) * wc),
                         f2bf((ohi * scall[c][cb + 3] + shall[c][cb + 3] + xhi) * wc));
            up2(ov.z, olo, ohi); up2(xv.z, xlo, xhi);
            hh.z = pack2(f2bf((olo * scall[c][cb + 4] + shall[c][cb + 4] + xlo) * wc),
                         f2bf((ohi * scall[c][cb + 5] + shall[c][cb + 5] + xhi) * wc));
            up2(ov.w, olo, ohi); up2(xv.w, xlo, xhi);
            hh.w = pack2(f2bf((olo * scall[c][cb + 6] + shall[c][cb + 6] + xlo) * wc),
                         f2bf((ohi * scall[c][cb + 7] + shall[c][cb + 7] + xhi) * wc));
            *(uint4*)((char*)As + ((eo * 2) ^ ((row & 7) << 4))) = hh;
        }
        const uint4* wsrc = (const uint4*)Wp;
#pragma unroll
        for (int it = 0; it < 4; ++it) {
            int qi = it * 512 + tid;
            uint4 v = wsrc[qi];
            int eo = qi * 8; int row = eo >> 7; int byte = eo * 2;
            *(uint4*)((char*)Bs + (byte ^ ((row & 7) << 4))) = v;
        }
        __syncthreads();
#pragma unroll
        for (int ks = 0; ks < 4; ++ks) {
            int kk = ks * 64 + lg * 16;
            int arow = wm * 16 + lr;
            short8 a = *(const short8*)((const char*)As + ((arow * 256 + kk) ^ ((arow & 7) << 4)));
#pragma unroll
            for (int nc = 0; nc < 4; ++nc) {
                int brow = wn * 64 + nc * 16 + lr;
                short8 b = *(const short8*)((const char*)Bs + ((brow * 256 + kk) ^ ((brow & 7) << 4)));
                acc[nc] = __builtin_amdgcn_mfma_f32_16x16x32_bf16(a, b, acc[nc], 0, 0, 0);
            }
        }
        __syncthreads();
    }
    // epilogue: add Sum_c wc*b1_c and write out once
    int nidx = bm * 4 + wm;
    int row0 = bm * 64 + wm * 16 + lg * 4;
    float wc8[8];
#pragma unroll
    for (int c = 0; c < 8; ++c) wc8[c] = comb8[c * NTOK + nidx];
#pragma unroll
    for (int nc = 0; nc < 4; ++nc) {
        int col = wn * 64 + nc * 16 + lr;
        float bias = 0.f;
#pragma unroll
        for (int c = 0; c < 8; ++c) {
            const float* b1 = (c < 4) ? (eb1 + c * 128) : (mb2 + (c - 4) * 128);
            bias += wc8[c] * b1[col];
        }
#pragma unroll
        for (int r = 0; r < 4; r++)
            out[(size_t)(row0 + r) * 128 + col] = acc[nc][r] + bias;
    }
}

extern "C" void kernel_launch(void* const* d_in, const int* in_sizes, int n_in,
                              void* d_out, int out_size, void* d_ws, size_t ws_size,
                              hipStream_t stream) {
    (void)in_sizes; (void)n_in; (void)ws_size; (void)out_size;
    const float* x    = (const float*)d_in[0];
    const float* mm   = (const float*)d_in[1];
    const float* tkv  = (const float*)d_in[2];
    const int*   idx  = (const int*)d_in[3];
    const int*   modi = (const int*)d_in[4];
    const float* Wr   = (const float*)d_in[5];
    const float* br   = (const float*)d_in[6];
    const float* eWq = (const float*)d_in[7],  *eWk = (const float*)d_in[8],  *eWv = (const float*)d_in[9];
    const float* eWo = (const float*)d_in[10], *eW1 = (const float*)d_in[11];
    const float* mWq = (const float*)d_in[12], *mWk = (const float*)d_in[13], *mWv = (const float*)d_in[14];
    const float* mWo = (const float*)d_in[15], *mW2 = (const float*)d_in[16];
    const float* ebq = (const float*)d_in[17], *ebk = (const float*)d_in[18], *ebv = (const float*)d_in[19];
    const float* ebo = (const float*)d_in[20], *eBeta = (const float*)d_in[21], *eb1 = (const float*)d_in[22];
    const float* mbq = (const float*)d_in[23], *mbk = (const float*)d_in[24], *mbv = (const float*)d_in[25];
    const float* mbo = (const float*)d_in[26], *mBeta = (const float*)d_in[27], *mb2 = (const float*)d_in[28];
    const float* eGamma = (const float*)d_in[29], *mGamma = (const float*)d_in[30];
    float* out = (float*)d_out;

    char* wsb = (char*)d_ws;
    const size_t MB = 1024 * 1024;
    u16* Xb = (u16*)wsb;                        // 0..4 MB
    u16* Wb = (u16*)(wsb + 4 * MB);             // 4..5.3 MB (40 x 16384 bf16)
    u16* Qb = (u16*)(wsb + 8 * MB);             // 8..40 MB  (attn O in-place)
    u16* Kb = (u16*)(wsb + 40 * MB);            // 40..72 MB
    u16* Vb = (u16*)(wsb + 72 * MB);            // 72..104 MB
    u16* O2 = (u16*)(wsb + 104 * MB);           // 104..136 MB (bf16)
    float* logits = (float*)(wsb + 136 * MB);
    float* comb8 = logits + 4096;               // [8][1024]
    float* mask8 = comb8 + 8192;                // [8][1024]
    float* cnt8  = mask8 + 8192;                // [8]
    float* bnsum = cnt8 + 16;                   // [8][128]
    float* bnsq  = bnsum + 1024;                // [8][128]

    k_prep<<<1360, 256, 0, stream>>>(x, eWq, eWk, eWv, eWo, eW1, mWq, mWk, mWv, mWo, mW2,
                                     mm, Wr, br, Xb, Wb, logits);
    k_route<<<1, 1024, 0, stream>>>(logits, modi, mask8, comb8, cnt8, bnsum, bnsq,
                                    out + (size_t)TT * DD);
    k_gemm_qkv<<<dim3(256, 8), 256, 0, stream>>>(Xb, Wb, ebq, mbq, mask8, Qb, Kb, Vb);
    k_attn<<<4096, 256, 0, stream>>>(Qb, Kb, Vb, tkv, idx, ebk, ebv, mbk, mbv, mask8, Qb);
    k_gemm_o<<<dim3(256, 8), 256, 0, stream>>>(Qb, Wb, ebo, mbo, O2, mask8, bnsum, bnsq);
    k_gemm_w1<<<256, 512, 0, stream>>>(O2, Xb, Wb, eb1, mb2, eGamma, mGamma, eBeta, mBeta,
                                       comb8, cnt8, bnsum, bnsq, out);
}